// Round 2
// baseline (4014.899 us; speedup 1.0000x reference)
//
#include <hip/hip_runtime.h>
#include <math.h>

typedef unsigned short u16;
typedef unsigned int u32;

#define Bn 16
#define Cc 256
#define Pp 4096
#define DHc 512
#define SCALE 0.25f

__device__ __forceinline__ float bf2f(u16 u) {
    return __uint_as_float(((u32)u) << 16);
}
__device__ __forceinline__ u16 f2bf(float f) {
    u32 u = __float_as_uint(f);
    u32 lsb = (u >> 16) & 1u;
    u += 0x7fffu + lsb;  // round-to-nearest-even
    return (u16)(u >> 16);
}

// ---------------------------------------------------------------- K1: means
// One block per (b,c) plane. xrow[b,c,h] = mean over w, xcol[b,c,w] = mean over h.
__global__ __launch_bounds__(256) void mean_kernel(
    const float* __restrict__ x, float* __restrict__ xrow, float* __restrict__ xcol) {
    __shared__ float plane[64][65];
    int bc = blockIdx.x;
    const float* xp = x + (size_t)bc * Pp;
    int tid = threadIdx.x;
#pragma unroll
    for (int k = 0; k < 16; ++k) {
        int idx = tid + k * 256;
        plane[idx >> 6][idx & 63] = xp[idx];
    }
    __syncthreads();
    if (tid < 64) {
        float s = 0.f;
#pragma unroll
        for (int w = 0; w < 64; ++w) s += plane[tid][w];
        xrow[bc * 64 + tid] = s * (1.f / 64.f);
    } else if (tid < 128) {
        int w = tid - 64;
        float s = 0.f;
#pragma unroll
        for (int h = 0; h < 64; ++h) s += plane[h][w];
        xcol[bc * 64 + w] = s * (1.f / 64.f);
    }
}

// ------------------------------------------------- K2: q/k/v embeddings (row & col)
// out channels 0..127 -> q, 128..255 -> k, 256..767 -> v. Pos interp added to q/k.
__global__ __launch_bounds__(256) void emb_kernel(
    const float* __restrict__ xrow, const float* __restrict__ xcol,
    const float* __restrict__ wq, const float* __restrict__ sq, const float* __restrict__ bq,
    const float* __restrict__ wk, const float* __restrict__ sk, const float* __restrict__ bk,
    const float* __restrict__ wv, const float* __restrict__ sv, const float* __restrict__ bv,
    const float* __restrict__ posrq, const float* __restrict__ posrk,
    const float* __restrict__ poscq, const float* __restrict__ posck,
    float* __restrict__ qrow, float* __restrict__ krow, float* __restrict__ vrow,
    float* __restrict__ qcol, float* __restrict__ kcol, float* __restrict__ vcol) {
    int branch = blockIdx.y;
    int t = blockIdx.x * 256 + threadIdx.x;  // 16*768*64 total
    int n = t & 63;
    int r = t >> 6;          // [0, 16*768)
    int b = r / 768;
    int oc = r - b * 768;    // [0,768)   (NOT a pow2 mask — 768 = 3*256)
    const float* xs = (branch ? xcol : xrow) + (size_t)b * Cc * 64 + n;

    const float* wr;
    if (oc < 128) wr = wq + oc * 256;
    else if (oc < 256) wr = wk + (oc - 128) * 256;
    else wr = wv + (oc - 256) * 256;

    float dot = 0.f;
#pragma unroll 8
    for (int i = 0; i < 256; ++i) dot += wr[i] * xs[i * 64];

    // linear interp of pos from 16 -> 64 (align_corners=False)
    float coords = 0.25f * (float)n - 0.375f;
    coords = fminf(fmaxf(coords, 0.f), 15.f);
    int lo = (int)floorf(coords);
    int hi = min(lo + 1, 15);
    float tt = coords - (float)lo;

    if (oc < 128) {
        int c = oc;
        const float* pos = branch ? poscq : posrq;
        float pv = pos[c * 16 + lo] * (1.f - tt) + pos[c * 16 + hi] * tt;
        float val = dot * sq[c] + bq[c] + pv;
        (branch ? qcol : qrow)[b * 8192 + c * 64 + n] = val;
    } else if (oc < 256) {
        int c = oc - 128;
        const float* pos = branch ? posck : posrk;
        float pv = pos[c * 16 + lo] * (1.f - tt) + pos[c * 16 + hi] * tt;
        float val = dot * sk[c] + bk[c] + pv;
        (branch ? kcol : krow)[b * 8192 + c * 64 + n] = val;
    } else {
        int c = oc - 256;
        float val = dot * sv[c] + bv[c];
        (branch ? vcol : vrow)[b * 32768 + c * 64 + n] = val;
    }
}

// ---------------------------------------------------------- K3: axial attention
// One 64-thread block per (b, head, branch). thread = query index n.
__global__ __launch_bounds__(64) void attn_kernel(
    const float* __restrict__ qr, const float* __restrict__ kr, const float* __restrict__ vr,
    const float* __restrict__ qc, const float* __restrict__ kc, const float* __restrict__ vc,
    float* __restrict__ xxr, float* __restrict__ xxc) {
    int branch = blockIdx.y;
    const float* q = branch ? qc : qr;
    const float* k = branch ? kc : kr;
    const float* v = branch ? vc : vr;
    float* xx = branch ? xxc : xxr;
    int bh = blockIdx.x;
    int b = bh >> 3, h = bh & 7;
    __shared__ float qs[16][64], ks[16][64], vs[64][64];
    int n = threadIdx.x;
#pragma unroll
    for (int c = 0; c < 16; ++c) {
        qs[c][n] = q[b * 8192 + (h * 16 + c) * 64 + n];
        ks[c][n] = k[b * 8192 + (h * 16 + c) * 64 + n];
    }
#pragma unroll
    for (int d = 0; d < 64; ++d)
        vs[d][n] = v[b * 32768 + (h * 64 + d) * 64 + n];
    __syncthreads();

    float qv[16];
#pragma unroll
    for (int c = 0; c < 16; ++c) qv[c] = qs[c][n];

    float s[64];
    float mx = -1e30f;
    for (int m = 0; m < 64; ++m) {
        float acc = 0.f;
#pragma unroll
        for (int c = 0; c < 16; ++c) acc += qv[c] * ks[c][m];
        acc *= SCALE;
        s[m] = acc;
        mx = fmaxf(mx, acc);
    }
    float sum = 0.f;
    for (int m = 0; m < 64; ++m) {
        s[m] = __expf(s[m] - mx);
        sum += s[m];
    }
    float inv = 1.f / sum;
    for (int d = 0; d < 64; ++d) {
        float acc = 0.f;
#pragma unroll 8
        for (int m = 0; m < 64; ++m) acc += s[m] * vs[d][m];
        xx[b * 32768 + (h * 64 + d) * 64 + n] = acc * inv;
    }
}

// ---------------------------------------- K4: post attention cbn (w_row / w_col)
__global__ __launch_bounds__(256) void post_kernel(
    const float* __restrict__ xxr, const float* __restrict__ xxc,
    const float* __restrict__ w_row, const float* __restrict__ s_row, const float* __restrict__ b_row,
    const float* __restrict__ w_col, const float* __restrict__ s_col, const float* __restrict__ b_col,
    float* __restrict__ xr2, float* __restrict__ xc2) {
    int branch = blockIdx.y;
    const float* xxp = branch ? xxc : xxr;
    const float* w = branch ? w_col : w_row;
    const float* ss = branch ? s_col : s_row;
    const float* bb = branch ? b_col : b_row;
    float* dst = branch ? xc2 : xr2;
    int t = blockIdx.x * 256 + threadIdx.x;  // 16*512*64 total
    int n = t & 63, o = (t >> 6) & 511, b = t >> 15;
    const float* xp = xxp + b * 32768 + n;
    const float* wr = w + o * 512;
    float dot = 0.f;
#pragma unroll 8
    for (int i = 0; i < 512; ++i) dot += fmaxf(xp[i * 64], 0.f) * wr[i];
    dst[t] = dot * ss[o] + bb[o];
}

// ---------------------------------------------------------- K5: gate sc GEMM
__global__ __launch_bounds__(256) void sc_kernel(
    const float* __restrict__ x, const float* __restrict__ w,
    const float* __restrict__ s, const float* __restrict__ bb, u16* __restrict__ sc) {
    int t = blockIdx.x * 256 + threadIdx.x;  // B*256*1024
    int pg = t & 1023, o = (t >> 10) & 255, b = t >> 18;
    int p0 = pg * 4;
    const float* xp = x + (size_t)b * Cc * Pp + p0;
    const float* wr = w + o * 256;
    float a0 = 0, a1 = 0, a2 = 0, a3 = 0;
#pragma unroll 4
    for (int i = 0; i < 256; ++i) {
        float4 xv = *reinterpret_cast<const float4*>(xp + (size_t)i * Pp);
        float wf = wr[i];
        a0 += wf * xv.x; a1 += wf * xv.y;
        a2 += wf * xv.z; a3 += wf * xv.w;
    }
    float sf = s[o], bf = bb[o];
    ushort4 out;
    out.x = f2bf(a0 * sf + bf); out.y = f2bf(a1 * sf + bf);
    out.z = f2bf(a2 * sf + bf); out.w = f2bf(a3 * sf + bf);
    *reinterpret_cast<ushort4*>(sc + (size_t)(b * 256 + o) * Pp + p0) = out;
}

// ------------------------------------------------- K6: depthwise 3x3 + affine + relu
__global__ __launch_bounds__(256) void dw_kernel(
    const u16* __restrict__ sc, const float* __restrict__ wdw,
    const float* __restrict__ sdw, const float* __restrict__ bdw, u16* __restrict__ dwout) {
    int t = blockIdx.x * 256 + threadIdx.x;  // B*256*4096
    int p = t & 4095, o = (t >> 12) & 255, b = t >> 20;
    int h = p >> 6, w = p & 63;
    const u16* base = sc + (size_t)(b * 256 + o) * Pp;
    float acc = 0.f;
#pragma unroll
    for (int ky = 0; ky < 3; ++ky) {
        int hh = h + ky - 1;
        if (hh < 0 || hh > 63) continue;
#pragma unroll
        for (int kx = 0; kx < 3; ++kx) {
            int ww = w + kx - 1;
            if (ww < 0 || ww > 63) continue;
            acc += wdw[o * 9 + ky * 3 + kx] * bf2f(base[hh * 64 + ww]);
        }
    }
    float v = acc * sdw[o] + bdw[o];
    dwout[t] = f2bf(fmaxf(v, 0.f));
}

// --------------------------- K7: a = relu(v + xx_row + xx_col), v = cbn(x, wv)
__global__ __launch_bounds__(256) void abuf_kernel(
    const float* __restrict__ x, const float* __restrict__ wv,
    const float* __restrict__ sv, const float* __restrict__ bv,
    const float* __restrict__ xr2, const float* __restrict__ xc2, u16* __restrict__ a) {
    int t = blockIdx.x * 256 + threadIdx.x;  // B*512*1024
    int pg = t & 1023, o = (t >> 10) & 511, b = t >> 19;
    int p0 = pg * 4;
    const float* xp = x + (size_t)b * Cc * Pp + p0;
    const float* wr = wv + o * 256;
    float a0 = 0, a1 = 0, a2 = 0, a3 = 0;
#pragma unroll 4
    for (int i = 0; i < 256; ++i) {
        float4 xv = *reinterpret_cast<const float4*>(xp + (size_t)i * Pp);
        float wf = wr[i];
        a0 += wf * xv.x; a1 += wf * xv.y;
        a2 += wf * xv.z; a3 += wf * xv.w;
    }
    float sf = sv[o], bf = bv[o];
    int h = p0 >> 6, w0 = p0 & 63;
    float rowadd = xr2[b * 32768 + o * 64 + h];
    const float* colp = xc2 + b * 32768 + o * 64;
    ushort4 out;
    out.x = f2bf(fmaxf(a0 * sf + bf + rowadd + colp[w0 + 0], 0.f));
    out.y = f2bf(fmaxf(a1 * sf + bf + rowadd + colp[w0 + 1], 0.f));
    out.z = f2bf(fmaxf(a2 * sf + bf + rowadd + colp[w0 + 2], 0.f));
    out.w = f2bf(fmaxf(a3 * sf + bf + rowadd + colp[w0 + 3], 0.f));
    *reinterpret_cast<ushort4*>(a + (size_t)(b * 512 + o) * Pp + p0) = out;
}

// ----------------------- K8: out = h_sigmoid(cbn(dwout,w_pw)) * cbn(a,w_proj)
__global__ __launch_bounds__(256) void final_kernel(
    const u16* __restrict__ a, const u16* __restrict__ dwout,
    const float* __restrict__ wproj, const float* __restrict__ sproj, const float* __restrict__ bproj,
    const float* __restrict__ wpw, const float* __restrict__ spw, const float* __restrict__ bpw,
    float* __restrict__ out) {
    int t = blockIdx.x * 256 + threadIdx.x;  // B*256*1024
    int pg = t & 1023, o = (t >> 10) & 255, b = t >> 18;
    int p0 = pg * 4;

    // proj dot over 512 channels of a
    const u16* ap = a + (size_t)b * DHc * Pp + p0;
    const float* wr = wproj + o * 512;
    float a0 = 0, a1 = 0, a2 = 0, a3 = 0;
#pragma unroll 4
    for (int j = 0; j < 512; ++j) {
        ushort4 av = *reinterpret_cast<const ushort4*>(ap + (size_t)j * Pp);
        float wf = wr[j];
        a0 += wf * bf2f(av.x); a1 += wf * bf2f(av.y);
        a2 += wf * bf2f(av.z); a3 += wf * bf2f(av.w);
    }
    float sf = sproj[o], bf = bproj[o];
    a0 = a0 * sf + bf; a1 = a1 * sf + bf; a2 = a2 * sf + bf; a3 = a3 * sf + bf;

    // pw dot over 256 channels of dwout
    const u16* dp = dwout + (size_t)b * Cc * Pp + p0;
    const float* wr2 = wpw + o * 256;
    float g0 = 0, g1 = 0, g2 = 0, g3 = 0;
#pragma unroll 4
    for (int i = 0; i < 256; ++i) {
        ushort4 dv = *reinterpret_cast<const ushort4*>(dp + (size_t)i * Pp);
        float wf = wr2[i];
        g0 += wf * bf2f(dv.x); g1 += wf * bf2f(dv.y);
        g2 += wf * bf2f(dv.z); g3 += wf * bf2f(dv.w);
    }
    float sf2 = spw[o], bf2v = bpw[o];
    g0 = fminf(fmaxf(g0 * sf2 + bf2v + 3.f, 0.f), 6.f) * (1.f / 6.f);
    g1 = fminf(fmaxf(g1 * sf2 + bf2v + 3.f, 0.f), 6.f) * (1.f / 6.f);
    g2 = fminf(fmaxf(g2 * sf2 + bf2v + 3.f, 0.f), 6.f) * (1.f / 6.f);
    g3 = fminf(fmaxf(g3 * sf2 + bf2v + 3.f, 0.f), 6.f) * (1.f / 6.f);

    float4 ov;
    ov.x = g0 * a0; ov.y = g1 * a1; ov.z = g2 * a2; ov.w = g3 * a3;
    *reinterpret_cast<float4*>(out + (size_t)(b * 256 + o) * Pp + p0) = ov;
}

extern "C" void kernel_launch(void* const* d_in, const int* in_sizes, int n_in,
                              void* d_out, int out_size, void* d_ws, size_t ws_size,
                              hipStream_t stream) {
    const float* x = (const float*)d_in[0];
    const float* wq = (const float*)d_in[1];
    const float* sq = (const float*)d_in[2];
    const float* bq = (const float*)d_in[3];
    const float* wk = (const float*)d_in[4];
    const float* sk = (const float*)d_in[5];
    const float* bk = (const float*)d_in[6];
    const float* wv = (const float*)d_in[7];
    const float* sv = (const float*)d_in[8];
    const float* bv = (const float*)d_in[9];
    const float* posrq = (const float*)d_in[10];
    const float* posrk = (const float*)d_in[11];
    const float* poscq = (const float*)d_in[12];
    const float* posck = (const float*)d_in[13];
    const float* w_row = (const float*)d_in[14];
    const float* s_row = (const float*)d_in[15];
    const float* b_row = (const float*)d_in[16];
    const float* w_col = (const float*)d_in[17];
    const float* s_col = (const float*)d_in[18];
    const float* b_col = (const float*)d_in[19];
    const float* w_proj = (const float*)d_in[20];
    const float* s_proj = (const float*)d_in[21];
    const float* b_proj = (const float*)d_in[22];
    const float* w_sc = (const float*)d_in[23];
    const float* s_sc = (const float*)d_in[24];
    const float* b_sc = (const float*)d_in[25];
    const float* w_dw = (const float*)d_in[26];
    const float* s_dw = (const float*)d_in[27];
    const float* b_dw = (const float*)d_in[28];
    const float* w_pw = (const float*)d_in[29];
    const float* s_pw = (const float*)d_in[30];
    const float* b_pw = (const float*)d_in[31];
    float* out = (float*)d_out;

    float* fws = (float*)d_ws;
    float* xrow = fws;                    // [B,C,64]  262144
    float* xcol = xrow + 262144;          // 262144
    float* qrow = xcol + 262144;          // 131072
    float* krow = qrow + 131072;
    float* qcol = krow + 131072;
    float* kcol = qcol + 131072;
    float* vrow = kcol + 131072;          // 524288
    float* vcol = vrow + 524288;
    float* xxr  = vcol + 524288;
    float* xxc  = xxr + 524288;
    float* xr2  = xxc + 524288;
    float* xc2  = xr2 + 524288;
    u16* sc    = (u16*)(xc2 + 524288);                 // B*256*4096 bf16
    u16* dwout = sc + (size_t)Bn * Cc * Pp;            // B*256*4096 bf16
    u16* abuf  = dwout + (size_t)Bn * Cc * Pp;         // B*512*4096 bf16

    mean_kernel<<<dim3(Bn * Cc), 256, 0, stream>>>(x, xrow, xcol);
    emb_kernel<<<dim3(3072, 2), 256, 0, stream>>>(
        xrow, xcol, wq, sq, bq, wk, sk, bk, wv, sv, bv,
        posrq, posrk, poscq, posck, qrow, krow, vrow, qcol, kcol, vcol);
    attn_kernel<<<dim3(128, 2), 64, 0, stream>>>(qrow, krow, vrow, qcol, kcol, vcol, xxr, xxc);
    post_kernel<<<dim3(2048, 2), 256, 0, stream>>>(
        xxr, xxc, w_row, s_row, b_row, w_col, s_col, b_col, xr2, xc2);
    sc_kernel<<<dim3(16384), 256, 0, stream>>>(x, w_sc, s_sc, b_sc, sc);
    dw_kernel<<<dim3(65536), 256, 0, stream>>>(sc, w_dw, s_dw, b_dw, dwout);
    abuf_kernel<<<dim3(32768), 256, 0, stream>>>(x, wv, sv, bv, xr2, xc2, abuf);
    final_kernel<<<dim3(16384), 256, 0, stream>>>(
        abuf, dwout, w_proj, s_proj, b_proj, w_pw, s_pw, b_pw, out);
}

// Round 3
// 763.083 us; speedup vs baseline: 5.2614x; 5.2614x over previous
//
#include <hip/hip_runtime.h>
#include <math.h>

typedef unsigned short u16;
typedef unsigned int u32;
typedef short short8 __attribute__((ext_vector_type(8)));
typedef float f32x4 __attribute__((ext_vector_type(4)));

#define Bn 16
#define Cc 256
#define Pp 4096
#define DHc 512
#define PTOT 65536   // Bn * Pp
#define SCALE 0.25f

__device__ __forceinline__ float bf2f(u16 u) {
    return __uint_as_float(((u32)u) << 16);
}
__device__ __forceinline__ u16 f2bf(float f) {
    u32 u = __float_as_uint(f);
    u32 lsb = (u >> 16) & 1u;
    u += 0x7fffu + lsb;  // round-to-nearest-even
    return (u16)(u >> 16);
}

// global -> LDS direct copy, 16 bytes per lane.
// AS1 = global (flat addr == AS1 addr); AS3 = LDS (low 32 bits of flat shared addr).
__device__ __forceinline__ void gload16(const u16* g, u16* l) {
    __builtin_amdgcn_global_load_lds(
        (const __attribute__((address_space(1))) void*)(uintptr_t)g,
        (__attribute__((address_space(3))) void*)(u32)(uintptr_t)l,
        16, 0, 0);
}

// ---------------------------------------------------------------- K1: means
__global__ __launch_bounds__(256) void mean_kernel(
    const float* __restrict__ x, float* __restrict__ xrow, float* __restrict__ xcol) {
    __shared__ float plane[64][65];
    int bc = blockIdx.x;
    const float* xp = x + (size_t)bc * Pp;
    int tid = threadIdx.x;
#pragma unroll
    for (int k = 0; k < 16; ++k) {
        int idx = tid + k * 256;
        plane[idx >> 6][idx & 63] = xp[idx];
    }
    __syncthreads();
    if (tid < 64) {
        float s = 0.f;
#pragma unroll
        for (int w = 0; w < 64; ++w) s += plane[tid][w];
        xrow[bc * 64 + tid] = s * (1.f / 64.f);
    } else if (tid < 128) {
        int w = tid - 64;
        float s = 0.f;
#pragma unroll
        for (int h = 0; h < 64; ++h) s += plane[h][w];
        xcol[bc * 64 + w] = s * (1.f / 64.f);
    }
}

// ------------------------------------------- K2: transpose x [b][c][p] -> xbf [b*P+p][c] bf16
__global__ __launch_bounds__(256) void xpose_kernel(
    const float* __restrict__ x, u16* __restrict__ xbf) {
    __shared__ float tile[64][65];
    int pb = blockIdx.x;  // p-tile (64)
    int cb = blockIdx.y;  // c-tile (4)
    int b = blockIdx.z;
    int t = threadIdx.x;
    int p_l = t & 63, c_q = t >> 6;
    const float* xp = x + ((size_t)b * Cc + cb * 64) * Pp + pb * 64;
#pragma unroll
    for (int rr = 0; rr < 16; ++rr) {
        int c_l = rr * 4 + c_q;
        tile[p_l][c_l] = xp[(size_t)c_l * Pp + p_l];
    }
    __syncthreads();
    int c_l2 = t & 63, p_q = t >> 6;
    u16* dst = xbf + ((size_t)b * Pp + pb * 64) * Cc + cb * 64;
#pragma unroll
    for (int rr = 0; rr < 16; ++rr) {
        int p_l2 = rr * 4 + p_q;
        dst[(size_t)p_l2 * Cc + c_l2] = f2bf(tile[p_l2][c_l2]);
    }
}

// ----------------------------------------------- K3: weights fp32 -> bf16 (layout kept [o][k])
__global__ __launch_bounds__(256) void wconv_kernel(
    const float* __restrict__ wv, const float* __restrict__ wsc,
    const float* __restrict__ wproj, const float* __restrict__ wpw,
    u16* __restrict__ wvb, u16* __restrict__ wscb,
    u16* __restrict__ wprojb, u16* __restrict__ wpwb) {
    int t = blockIdx.x * 256 + threadIdx.x;  // 393216
    if (t < 131072) wvb[t] = f2bf(wv[t]);
    else if (t < 196608) wscb[t - 131072] = f2bf(wsc[t - 131072]);
    else if (t < 327680) wprojb[t - 196608] = f2bf(wproj[t - 196608]);
    else wpwb[t - 327680] = f2bf(wpw[t - 327680]);
}

// ------------------------------------------------- K4: q/k/v embeddings (row & col)
__global__ __launch_bounds__(256) void emb_kernel(
    const float* __restrict__ xrow, const float* __restrict__ xcol,
    const float* __restrict__ wq, const float* __restrict__ sq, const float* __restrict__ bq,
    const float* __restrict__ wk, const float* __restrict__ sk, const float* __restrict__ bk,
    const float* __restrict__ wv, const float* __restrict__ sv, const float* __restrict__ bv,
    const float* __restrict__ posrq, const float* __restrict__ posrk,
    const float* __restrict__ poscq, const float* __restrict__ posck,
    float* __restrict__ qrow, float* __restrict__ krow, float* __restrict__ vrow,
    float* __restrict__ qcol, float* __restrict__ kcol, float* __restrict__ vcol) {
    int branch = blockIdx.y;
    int t = blockIdx.x * 256 + threadIdx.x;
    int n = t & 63;
    int r = t >> 6;
    int b = r / 768;
    int oc = r - b * 768;
    const float* xs = (branch ? xcol : xrow) + (size_t)b * Cc * 64 + n;

    const float* wr;
    if (oc < 128) wr = wq + oc * 256;
    else if (oc < 256) wr = wk + (oc - 128) * 256;
    else wr = wv + (oc - 256) * 256;

    float dot = 0.f;
#pragma unroll 8
    for (int i = 0; i < 256; ++i) dot += wr[i] * xs[i * 64];

    float coords = 0.25f * (float)n - 0.375f;
    coords = fminf(fmaxf(coords, 0.f), 15.f);
    int lo = (int)floorf(coords);
    int hi = min(lo + 1, 15);
    float tt = coords - (float)lo;

    if (oc < 128) {
        int c = oc;
        const float* pos = branch ? poscq : posrq;
        float pv = pos[c * 16 + lo] * (1.f - tt) + pos[c * 16 + hi] * tt;
        float val = dot * sq[c] + bq[c] + pv;
        (branch ? qcol : qrow)[b * 8192 + c * 64 + n] = val;
    } else if (oc < 256) {
        int c = oc - 128;
        const float* pos = branch ? posck : posrk;
        float pv = pos[c * 16 + lo] * (1.f - tt) + pos[c * 16 + hi] * tt;
        float val = dot * sk[c] + bk[c] + pv;
        (branch ? kcol : krow)[b * 8192 + c * 64 + n] = val;
    } else {
        int c = oc - 256;
        float val = dot * sv[c] + bv[c];
        (branch ? vcol : vrow)[b * 32768 + c * 64 + n] = val;
    }
}

// ---------------------------------------------------------- K5: axial attention
__global__ __launch_bounds__(64) void attn_kernel(
    const float* __restrict__ qr, const float* __restrict__ kr, const float* __restrict__ vr,
    const float* __restrict__ qc, const float* __restrict__ kc, const float* __restrict__ vc,
    float* __restrict__ xxr, float* __restrict__ xxc) {
    int branch = blockIdx.y;
    const float* q = branch ? qc : qr;
    const float* k = branch ? kc : kr;
    const float* v = branch ? vc : vr;
    float* xx = branch ? xxc : xxr;
    int bh = blockIdx.x;
    int b = bh >> 3, h = bh & 7;
    __shared__ float qs[16][64], ks[16][64], vs[64][64];
    int n = threadIdx.x;
#pragma unroll
    for (int c = 0; c < 16; ++c) {
        qs[c][n] = q[b * 8192 + (h * 16 + c) * 64 + n];
        ks[c][n] = k[b * 8192 + (h * 16 + c) * 64 + n];
    }
#pragma unroll
    for (int d = 0; d < 64; ++d)
        vs[d][n] = v[b * 32768 + (h * 64 + d) * 64 + n];
    __syncthreads();

    float qv[16];
#pragma unroll
    for (int c = 0; c < 16; ++c) qv[c] = qs[c][n];

    float s[64];
    float mx = -1e30f;
    for (int m = 0; m < 64; ++m) {
        float acc = 0.f;
#pragma unroll
        for (int c = 0; c < 16; ++c) acc += qv[c] * ks[c][m];
        acc *= SCALE;
        s[m] = acc;
        mx = fmaxf(mx, acc);
    }
    float sum = 0.f;
    for (int m = 0; m < 64; ++m) {
        s[m] = __expf(s[m] - mx);
        sum += s[m];
    }
    float inv = 1.f / sum;
    for (int d = 0; d < 64; ++d) {
        float acc = 0.f;
#pragma unroll 8
        for (int m = 0; m < 64; ++m) acc += s[m] * vs[d][m];
        xx[b * 32768 + (h * 64 + d) * 64 + n] = acc * inv;
    }
}

// ------------------- K6: post attention cbn. OUTPUT LAYOUT [b][n][o] (o contiguous)
__global__ __launch_bounds__(256) void post_kernel(
    const float* __restrict__ xxr, const float* __restrict__ xxc,
    const float* __restrict__ w_row, const float* __restrict__ s_row, const float* __restrict__ b_row,
    const float* __restrict__ w_col, const float* __restrict__ s_col, const float* __restrict__ b_col,
    float* __restrict__ xr2, float* __restrict__ xc2) {
    int branch = blockIdx.y;
    const float* xxp = branch ? xxc : xxr;
    const float* w = branch ? w_col : w_row;
    const float* ss = branch ? s_col : s_row;
    const float* bb = branch ? b_col : b_row;
    float* dst = branch ? xc2 : xr2;
    int t = blockIdx.x * 256 + threadIdx.x;
    int n = t & 63, o = (t >> 6) & 511, b = t >> 15;
    const float* xp = xxp + b * 32768 + n;
    const float* wr = w + o * 512;
    float dot = 0.f;
#pragma unroll 8
    for (int i = 0; i < 512; ++i) dot += fmaxf(xp[i * 64], 0.f) * wr[i];
    dst[b * 32768 + n * 512 + o] = dot * ss[o] + bb[o];
}

// ------------------------------------------------------------- MFMA GEMM mainloop
// D[o][p] = sum_k W[o][k] * X[p][k], 128x128 tile, BK=32, 4 waves (2x2 of 64x64).
// A-operand = W rows (m = out-channel), B-operand = X rows (n = pixel).
__device__ __forceinline__ void gemm_mainloop(
    const u16* __restrict__ W, const u16* __restrict__ X, int K,
    int o0, size_t prow0, u16* ldsA, u16* ldsB, f32x4 (&acc)[4][4]) {
    int t = threadIdx.x;
    int w = t >> 6, lane = t & 63;
    // staging map: per wave, 2 chunks of (64 lanes x 16B); row = w*32 + i*16 + lane/4
    int sr = (w << 5) + (lane >> 2);
    int ks = (lane & 3) * 8;
    const u16* gA = W + (size_t)(o0 + sr) * K + ks;
    const u16* gB = X + (prow0 + sr) * K + ks;
    u16* lA = ldsA + sr * 32 + ks;
    u16* lB = ldsB + sr * 32 + ks;
    // fragment read base
    int wo = (w >> 1) * 64, wp = (w & 1) * 64;
    const u16* fA = ldsA + (wo + (lane & 15)) * 32 + ((lane >> 4) * 8);
    const u16* fB = ldsB + (wp + (lane & 15)) * 32 + ((lane >> 4) * 8);

    for (int k0 = 0; k0 < K; k0 += 32) {
        if (k0) __syncthreads();
        gload16(gA + k0, lA);
        gload16(gA + k0 + (size_t)16 * K, lA + 16 * 32);
        gload16(gB + k0, lB);
        gload16(gB + k0 + (size_t)16 * K, lB + 16 * 32);
        __syncthreads();
        short8 a[4], b[4];
#pragma unroll
        for (int i = 0; i < 4; ++i) a[i] = *(const short8*)(fA + i * 16 * 32);
#pragma unroll
        for (int j = 0; j < 4; ++j) b[j] = *(const short8*)(fB + j * 16 * 32);
#pragma unroll
        for (int i = 0; i < 4; ++i)
#pragma unroll
            for (int j = 0; j < 4; ++j)
                acc[i][j] = __builtin_amdgcn_mfma_f32_16x16x32_bf16(a[i], b[j], acc[i][j], 0, 0, 0);
    }
}

// epilogue index helpers: frag(i,j), lane -> o = o0+wo+i*16+quad*4+r ; p = prow0+wp+j*16+cn

// ------------------------------------- G1: sc = cbn(x, w_sc)  -> scb bf16 [p][256]
__global__ __launch_bounds__(256) void gemm_sc(
    const u16* __restrict__ Wb, const u16* __restrict__ X,
    const float* __restrict__ s, const float* __restrict__ bb, u16* __restrict__ outb) {
    __shared__ u16 ldsA[128 * 32];
    __shared__ u16 ldsB[128 * 32];
    f32x4 acc[4][4];
#pragma unroll
    for (int i = 0; i < 4; ++i)
#pragma unroll
        for (int j = 0; j < 4; ++j) acc[i][j] = (f32x4){0.f, 0.f, 0.f, 0.f};
    int o0 = blockIdx.x * 128;
    size_t prow0 = (size_t)blockIdx.y * 128;
    gemm_mainloop(Wb, X, 256, o0, prow0, ldsA, ldsB, acc);

    int lane = threadIdx.x & 63, w = threadIdx.x >> 6;
    int wo = (w >> 1) * 64, wp = (w & 1) * 64;
    int quad = lane >> 4, cn = lane & 15;
#pragma unroll
    for (int i = 0; i < 4; ++i) {
        int ob = o0 + wo + i * 16 + quad * 4;
        f32x4 s4 = *(const f32x4*)&s[ob];
        f32x4 b4 = *(const f32x4*)&bb[ob];
#pragma unroll
        for (int j = 0; j < 4; ++j) {
            size_t p = prow0 + wp + j * 16 + cn;
            ushort4 o4;
            o4.x = f2bf(acc[i][j][0] * s4[0] + b4[0]);
            o4.y = f2bf(acc[i][j][1] * s4[1] + b4[1]);
            o4.z = f2bf(acc[i][j][2] * s4[2] + b4[2]);
            o4.w = f2bf(acc[i][j][3] * s4[3] + b4[3]);
            *(ushort4*)&outb[p * 256 + ob] = o4;
        }
    }
}

// ------------- G2: abuf = relu(cbn(x,wv) + xr2 + xc2) -> bf16 [p][512]
__global__ __launch_bounds__(256) void gemm_v(
    const u16* __restrict__ Wb, const u16* __restrict__ X,
    const float* __restrict__ s, const float* __restrict__ bb,
    const float* __restrict__ xr2, const float* __restrict__ xc2, u16* __restrict__ outb) {
    __shared__ u16 ldsA[128 * 32];
    __shared__ u16 ldsB[128 * 32];
    f32x4 acc[4][4];
#pragma unroll
    for (int i = 0; i < 4; ++i)
#pragma unroll
        for (int j = 0; j < 4; ++j) acc[i][j] = (f32x4){0.f, 0.f, 0.f, 0.f};
    int o0 = blockIdx.x * 128;
    size_t prow0 = (size_t)blockIdx.y * 128;
    gemm_mainloop(Wb, X, 256, o0, prow0, ldsA, ldsB, acc);

    int lane = threadIdx.x & 63, w = threadIdx.x >> 6;
    int wo = (w >> 1) * 64, wp = (w & 1) * 64;
    int quad = lane >> 4, cn = lane & 15;
#pragma unroll
    for (int i = 0; i < 4; ++i) {
        int ob = o0 + wo + i * 16 + quad * 4;
        f32x4 s4 = *(const f32x4*)&s[ob];
        f32x4 b4 = *(const f32x4*)&bb[ob];
#pragma unroll
        for (int j = 0; j < 4; ++j) {
            size_t p = prow0 + wp + j * 16 + cn;
            int bi = (int)(p >> 12), hh = (int)((p >> 6) & 63), ww = (int)(p & 63);
            f32x4 ra = *(const f32x4*)&xr2[(size_t)bi * 32768 + hh * 512 + ob];
            f32x4 ca = *(const f32x4*)&xc2[(size_t)bi * 32768 + ww * 512 + ob];
            ushort4 o4;
            o4.x = f2bf(fmaxf(acc[i][j][0] * s4[0] + b4[0] + ra[0] + ca[0], 0.f));
            o4.y = f2bf(fmaxf(acc[i][j][1] * s4[1] + b4[1] + ra[1] + ca[1], 0.f));
            o4.z = f2bf(fmaxf(acc[i][j][2] * s4[2] + b4[2] + ra[2] + ca[2], 0.f));
            o4.w = f2bf(fmaxf(acc[i][j][3] * s4[3] + b4[3] + ra[3] + ca[3], 0.f));
            *(ushort4*)&outb[p * 512 + ob] = o4;
        }
    }
}

// ------------- G3: gate = h_sigmoid(cbn(dwout, w_pw)) -> bf16 [p][256]
__global__ __launch_bounds__(256) void gemm_pw(
    const u16* __restrict__ Wb, const u16* __restrict__ X,
    const float* __restrict__ s, const float* __restrict__ bb, u16* __restrict__ outb) {
    __shared__ u16 ldsA[128 * 32];
    __shared__ u16 ldsB[128 * 32];
    f32x4 acc[4][4];
#pragma unroll
    for (int i = 0; i < 4; ++i)
#pragma unroll
        for (int j = 0; j < 4; ++j) acc[i][j] = (f32x4){0.f, 0.f, 0.f, 0.f};
    int o0 = blockIdx.x * 128;
    size_t prow0 = (size_t)blockIdx.y * 128;
    gemm_mainloop(Wb, X, 256, o0, prow0, ldsA, ldsB, acc);

    int lane = threadIdx.x & 63, w = threadIdx.x >> 6;
    int wo = (w >> 1) * 64, wp = (w & 1) * 64;
    int quad = lane >> 4, cn = lane & 15;
#pragma unroll
    for (int i = 0; i < 4; ++i) {
        int ob = o0 + wo + i * 16 + quad * 4;
        f32x4 s4 = *(const f32x4*)&s[ob];
        f32x4 b4 = *(const f32x4*)&bb[ob];
#pragma unroll
        for (int j = 0; j < 4; ++j) {
            size_t p = prow0 + wp + j * 16 + cn;
            ushort4 o4;
            o4.x = f2bf(fminf(fmaxf(acc[i][j][0] * s4[0] + b4[0] + 3.f, 0.f), 6.f) * (1.f / 6.f));
            o4.y = f2bf(fminf(fmaxf(acc[i][j][1] * s4[1] + b4[1] + 3.f, 0.f), 6.f) * (1.f / 6.f));
            o4.z = f2bf(fminf(fmaxf(acc[i][j][2] * s4[2] + b4[2] + 3.f, 0.f), 6.f) * (1.f / 6.f));
            o4.w = f2bf(fminf(fmaxf(acc[i][j][3] * s4[3] + b4[3] + 3.f, 0.f), 6.f) * (1.f / 6.f));
            *(ushort4*)&outb[p * 256 + ob] = o4;
        }
    }
}

// ------------- G4: out[b][o][p] = gate[p][o] * cbn(abuf, w_proj)   (K=512, fp32 out)
__global__ __launch_bounds__(256) void gemm_proj(
    const u16* __restrict__ Wb, const u16* __restrict__ X,
    const float* __restrict__ s, const float* __restrict__ bb,
    const u16* __restrict__ gate, float* __restrict__ out) {
    __shared__ u16 ldsA[128 * 32];
    __shared__ u16 ldsB[128 * 32];
    f32x4 acc[4][4];
#pragma unroll
    for (int i = 0; i < 4; ++i)
#pragma unroll
        for (int j = 0; j < 4; ++j) acc[i][j] = (f32x4){0.f, 0.f, 0.f, 0.f};
    int o0 = blockIdx.x * 128;
    size_t prow0 = (size_t)blockIdx.y * 128;
    gemm_mainloop(Wb, X, 512, o0, prow0, ldsA, ldsB, acc);

    int lane = threadIdx.x & 63, w = threadIdx.x >> 6;
    int wo = (w >> 1) * 64, wp = (w & 1) * 64;
    int quad = lane >> 4, cn = lane & 15;
#pragma unroll
    for (int i = 0; i < 4; ++i) {
        int ob = o0 + wo + i * 16 + quad * 4;
        f32x4 s4 = *(const f32x4*)&s[ob];
        f32x4 b4 = *(const f32x4*)&bb[ob];
#pragma unroll
        for (int j = 0; j < 4; ++j) {
            size_t p = prow0 + wp + j * 16 + cn;
            int bi = (int)(p >> 12), pl = (int)(p & 4095);
            ushort4 gv = *(const ushort4*)&gate[p * 256 + ob];
            float* op = out + (size_t)bi * 1048576 + (size_t)ob * 4096 + pl;
            op[0 * 4096] = bf2f(gv.x) * (acc[i][j][0] * s4[0] + b4[0]);
            op[1 * 4096] = bf2f(gv.y) * (acc[i][j][1] * s4[1] + b4[1]);
            op[2 * 4096] = bf2f(gv.z) * (acc[i][j][2] * s4[2] + b4[2]);
            op[3 * 4096] = bf2f(gv.w) * (acc[i][j][3] * s4[3] + b4[3]);
        }
    }
}

// ------------------------------- K7: depthwise 3x3 + affine + relu, [p][c] layout
__global__ __launch_bounds__(256) void dw_kernel(
    const u16* __restrict__ sc, const float* __restrict__ wdw,
    const float* __restrict__ sdw, const float* __restrict__ bdw, u16* __restrict__ dwout) {
    int t = blockIdx.x * 256 + threadIdx.x;  // B*P*C
    int c = t & 255;
    size_t p = (size_t)(t >> 8);
    int h = (int)((p >> 6) & 63), ww = (int)(p & 63);
    float acc = 0.f;
#pragma unroll
    for (int ky = 0; ky < 3; ++ky) {
        int hh = h + ky - 1;
        if (hh < 0 || hh > 63) continue;
#pragma unroll
        for (int kx = 0; kx < 3; ++kx) {
            int wx = ww + kx - 1;
            if (wx < 0 || wx > 63) continue;
            acc += wdw[c * 9 + ky * 3 + kx] *
                   bf2f(sc[(p + (size_t)((ky - 1) * 64 + (kx - 1))) * 256 + c]);
        }
    }
    float v = acc * sdw[c] + bdw[c];
    dwout[(size_t)t] = f2bf(fmaxf(v, 0.f));
}

extern "C" void kernel_launch(void* const* d_in, const int* in_sizes, int n_in,
                              void* d_out, int out_size, void* d_ws, size_t ws_size,
                              hipStream_t stream) {
    const float* x = (const float*)d_in[0];
    const float* wq = (const float*)d_in[1];
    const float* sq = (const float*)d_in[2];
    const float* bq = (const float*)d_in[3];
    const float* wk = (const float*)d_in[4];
    const float* sk = (const float*)d_in[5];
    const float* bk = (const float*)d_in[6];
    const float* wv = (const float*)d_in[7];
    const float* sv = (const float*)d_in[8];
    const float* bv = (const float*)d_in[9];
    const float* posrq = (const float*)d_in[10];
    const float* posrk = (const float*)d_in[11];
    const float* poscq = (const float*)d_in[12];
    const float* posck = (const float*)d_in[13];
    const float* w_row = (const float*)d_in[14];
    const float* s_row = (const float*)d_in[15];
    const float* b_row = (const float*)d_in[16];
    const float* w_col = (const float*)d_in[17];
    const float* s_col = (const float*)d_in[18];
    const float* b_col = (const float*)d_in[19];
    const float* w_proj = (const float*)d_in[20];
    const float* s_proj = (const float*)d_in[21];
    const float* b_proj = (const float*)d_in[22];
    const float* w_sc = (const float*)d_in[23];
    const float* s_sc = (const float*)d_in[24];
    const float* b_sc = (const float*)d_in[25];
    const float* w_dw = (const float*)d_in[26];
    const float* s_dw = (const float*)d_in[27];
    const float* b_dw = (const float*)d_in[28];
    const float* w_pw = (const float*)d_in[29];
    const float* s_pw = (const float*)d_in[30];
    const float* b_pw = (const float*)d_in[31];
    float* out = (float*)d_out;

    float* fws = (float*)d_ws;
    float* xrow = fws;
    float* xcol = xrow + 262144;
    float* qrow = xcol + 262144;
    float* krow = qrow + 131072;
    float* qcol = krow + 131072;
    float* kcol = qcol + 131072;
    float* vrow = kcol + 131072;
    float* vcol = vrow + 524288;
    float* xxr  = vcol + 524288;
    float* xxc  = xxr + 524288;
    float* xr2  = xxc + 524288;   // [b][n][o=512]
    float* xc2  = xr2 + 524288;
    u16* xbf    = (u16*)(xc2 + 524288);            // [65536][256]
    u16* wvb    = xbf + (size_t)PTOT * 256;        // [512][256]
    u16* wscb   = wvb + 131072;                    // [256][256]
    u16* wprojb = wscb + 65536;                    // [256][512]
    u16* wpwb   = wprojb + 131072;                 // [256][256]
    u16* scb    = wpwb + 65536;                    // [65536][256] (later reused as gate)
    u16* dwb    = scb + (size_t)PTOT * 256;        // [65536][256]
    u16* abuf   = dwb + (size_t)PTOT * 256;        // [65536][512]
    u16* gate   = scb;                             // alias: sc dead after dw_kernel

    mean_kernel<<<dim3(Bn * Cc), 256, 0, stream>>>(x, xrow, xcol);
    xpose_kernel<<<dim3(64, 4, Bn), 256, 0, stream>>>(x, xbf);
    wconv_kernel<<<dim3(1536), 256, 0, stream>>>(wv, w_sc, w_proj, w_pw, wvb, wscb, wprojb, wpwb);
    emb_kernel<<<dim3(3072, 2), 256, 0, stream>>>(
        xrow, xcol, wq, sq, bq, wk, sk, bk, wv, sv, bv,
        posrq, posrk, poscq, posck, qrow, krow, vrow, qcol, kcol, vcol);
    attn_kernel<<<dim3(128, 2), 64, 0, stream>>>(qrow, krow, vrow, qcol, kcol, vcol, xxr, xxc);
    post_kernel<<<dim3(2048, 2), 256, 0, stream>>>(
        xxr, xxc, w_row, s_row, b_row, w_col, s_col, b_col, xr2, xc2);
    gemm_sc<<<dim3(2, 512), 256, 0, stream>>>(wscb, xbf, s_sc, b_sc, scb);
    dw_kernel<<<dim3(65536), 256, 0, stream>>>(scb, w_dw, s_dw, b_dw, dwb);
    gemm_v<<<dim3(4, 512), 256, 0, stream>>>(wvb, xbf, sv, bv, xr2, xc2, abuf);
    gemm_pw<<<dim3(2, 512), 256, 0, stream>>>(wpwb, dwb, s_pw, b_pw, gate);
    gemm_proj<<<dim3(2, 512), 256, 0, stream>>>(wprojb, abuf, s_proj, b_proj, gate, out);
}

// Round 4
// 717.292 us; speedup vs baseline: 5.5973x; 1.0638x over previous
//
#include <hip/hip_runtime.h>
#include <math.h>

typedef unsigned short u16;
typedef unsigned int u32;
typedef short short8 __attribute__((ext_vector_type(8)));
typedef float f32x4 __attribute__((ext_vector_type(4)));

#define Bn 16
#define Cc 256
#define Pp 4096
#define DHc 512
#define PTOT 65536   // Bn * Pp
#define SCALE 0.25f

__device__ __forceinline__ float bf2f(u16 u) {
    return __uint_as_float(((u32)u) << 16);
}
__device__ __forceinline__ u16 f2bf(float f) {
    u32 u = __float_as_uint(f);
    u32 lsb = (u >> 16) & 1u;
    u += 0x7fffu + lsb;  // round-to-nearest-even
    return (u16)(u >> 16);
}

// global -> LDS direct copy, 16 bytes per lane (LDS dest must be base + lane*16).
__device__ __forceinline__ void gload16(const u16* g, u16* l) {
    __builtin_amdgcn_global_load_lds(
        (const __attribute__((address_space(1))) void*)(uintptr_t)g,
        (__attribute__((address_space(3))) void*)(u32)(uintptr_t)l,
        16, 0, 0);
}

// ------------------------- K1: means, transposed output xrowT/xcolT [b][n][c]
__global__ __launch_bounds__(256) void mean_kernel(
    const float* __restrict__ x, float* __restrict__ xrowT, float* __restrict__ xcolT) {
    __shared__ float plane[64][65];
    int bc = blockIdx.x;
    int b = bc >> 8, c = bc & 255;
    const float* xp = x + (size_t)bc * Pp;
    int tid = threadIdx.x;
#pragma unroll
    for (int k = 0; k < 16; ++k) {
        int idx = tid + k * 256;
        plane[idx >> 6][idx & 63] = xp[idx];
    }
    __syncthreads();
    if (tid < 64) {
        float s = 0.f;
#pragma unroll
        for (int w = 0; w < 64; ++w) s += plane[tid][w];
        xrowT[((size_t)b * 64 + tid) * 256 + c] = s * (1.f / 64.f);
    } else if (tid < 128) {
        int w = tid - 64;
        float s = 0.f;
#pragma unroll
        for (int h = 0; h < 64; ++h) s += plane[h][w];
        xcolT[((size_t)b * 64 + w) * 256 + c] = s * (1.f / 64.f);
    }
}

// --------------------- K2: transpose x [b][c][p] -> xbf [b*P+p][c] bf16
__global__ __launch_bounds__(256) void xpose_kernel(
    const float* __restrict__ x, u16* __restrict__ xbf) {
    __shared__ float tile[64][65];
    int pb = blockIdx.x;
    int cb = blockIdx.y;
    int b = blockIdx.z;
    int t = threadIdx.x;
    int p_l = t & 63, c_q = t >> 6;
    const float* xp = x + ((size_t)b * Cc + cb * 64) * Pp + pb * 64;
#pragma unroll
    for (int rr = 0; rr < 16; ++rr) {
        int c_l = rr * 4 + c_q;
        tile[p_l][c_l] = xp[(size_t)c_l * Pp + p_l];
    }
    __syncthreads();
    int c_l2 = t & 63, p_q = t >> 6;
    u16* dst = xbf + ((size_t)b * Pp + pb * 64) * Cc + cb * 64;
#pragma unroll
    for (int rr = 0; rr < 16; ++rr) {
        int p_l2 = rr * 4 + p_q;
        dst[(size_t)p_l2 * Cc + c_l2] = f2bf(tile[p_l2][c_l2]);
    }
}

// -------------- K3: weights fp32 -> bf16 ([o][k] kept) + dw weight transpose
__global__ __launch_bounds__(256) void wconv_kernel(
    const float* __restrict__ wv, const float* __restrict__ wsc,
    const float* __restrict__ wproj, const float* __restrict__ wpw,
    const float* __restrict__ wrow, const float* __restrict__ wcol,
    const float* __restrict__ wdw,
    u16* __restrict__ wvb, u16* __restrict__ wscb,
    u16* __restrict__ wprojb, u16* __restrict__ wpwb,
    u16* __restrict__ wrb, u16* __restrict__ wcb, float* __restrict__ wdwT) {
    int t = blockIdx.x * 256 + threadIdx.x;  // 917504 total
    if (t < 2304) wdwT[(t % 9) * 256 + (t / 9)] = wdw[t];
    if (t < 131072) wvb[t] = f2bf(wv[t]);
    else if (t < 196608) wscb[t - 131072] = f2bf(wsc[t - 131072]);
    else if (t < 327680) wprojb[t - 196608] = f2bf(wproj[t - 196608]);
    else if (t < 393216) wpwb[t - 327680] = f2bf(wpw[t - 327680]);
    else if (t < 655360) wrb[t - 393216] = f2bf(wrow[t - 393216]);
    else wcb[t - 655360] = f2bf(wcol[t - 655360]);
}

// ------------------------- K4: q/k/v embeddings (row & col), k-contiguous reads
__global__ __launch_bounds__(256) void emb_kernel(
    const float* __restrict__ xrowT, const float* __restrict__ xcolT,
    const float* __restrict__ wq, const float* __restrict__ sq, const float* __restrict__ bq,
    const float* __restrict__ wk, const float* __restrict__ sk, const float* __restrict__ bk,
    const float* __restrict__ wv, const float* __restrict__ sv, const float* __restrict__ bv,
    const float* __restrict__ posrq, const float* __restrict__ posrk,
    const float* __restrict__ poscq, const float* __restrict__ posck,
    float* __restrict__ qrow, float* __restrict__ krow, float* __restrict__ vrow,
    float* __restrict__ qcol, float* __restrict__ kcol, float* __restrict__ vcol) {
    int branch = blockIdx.y;
    int t = blockIdx.x * 256 + threadIdx.x;
    int n = t & 63;
    int r = t >> 6;
    int b = r / 768;
    int oc = r - b * 768;
    const float* xs = (branch ? xcolT : xrowT) + ((size_t)b * 64 + n) * 256;

    const float* wr;
    if (oc < 128) wr = wq + oc * 256;
    else if (oc < 256) wr = wk + (oc - 128) * 256;
    else wr = wv + (oc - 256) * 256;

    float dot = 0.f;
    const f32x4* xv4 = (const f32x4*)xs;
    const f32x4* wv4 = (const f32x4*)wr;
#pragma unroll 8
    for (int i = 0; i < 64; ++i) {
        f32x4 a = xv4[i], c = wv4[i];
        dot += a[0] * c[0] + a[1] * c[1] + a[2] * c[2] + a[3] * c[3];
    }

    float coords = 0.25f * (float)n - 0.375f;
    coords = fminf(fmaxf(coords, 0.f), 15.f);
    int lo = (int)floorf(coords);
    int hi = min(lo + 1, 15);
    float tt = coords - (float)lo;

    if (oc < 128) {
        int c = oc;
        const float* pos = branch ? poscq : posrq;
        float pv = pos[c * 16 + lo] * (1.f - tt) + pos[c * 16 + hi] * tt;
        float val = dot * sq[c] + bq[c] + pv;
        (branch ? qcol : qrow)[b * 8192 + c * 64 + n] = val;
    } else if (oc < 256) {
        int c = oc - 128;
        const float* pos = branch ? posck : posrk;
        float pv = pos[c * 16 + lo] * (1.f - tt) + pos[c * 16 + hi] * tt;
        float val = dot * sk[c] + bk[c] + pv;
        (branch ? kcol : krow)[b * 8192 + c * 64 + n] = val;
    } else {
        int c = oc - 256;
        float val = dot * sv[c] + bv[c];
        (branch ? vcol : vrow)[b * 32768 + c * 64 + n] = val;
    }
}

// ---------------- K5: axial attention; emits relu(xx) bf16 transposed [b][br][n][i]
__global__ __launch_bounds__(64) void attn_kernel(
    const float* __restrict__ qr, const float* __restrict__ kr, const float* __restrict__ vr,
    const float* __restrict__ qc, const float* __restrict__ kc, const float* __restrict__ vc,
    u16* __restrict__ xxbf) {
    int branch = blockIdx.y;
    const float* q = branch ? qc : qr;
    const float* k = branch ? kc : kr;
    const float* v = branch ? vc : vr;
    int bh = blockIdx.x;
    int b = bh >> 3, h = bh & 7;
    __shared__ float qs[16][64], ks[16][64], vs[64][64];
    int n = threadIdx.x;
#pragma unroll
    for (int c = 0; c < 16; ++c) {
        qs[c][n] = q[b * 8192 + (h * 16 + c) * 64 + n];
        ks[c][n] = k[b * 8192 + (h * 16 + c) * 64 + n];
    }
#pragma unroll
    for (int d = 0; d < 64; ++d)
        vs[d][n] = v[b * 32768 + (h * 64 + d) * 64 + n];
    __syncthreads();

    float qv[16];
#pragma unroll
    for (int c = 0; c < 16; ++c) qv[c] = qs[c][n];

    float s[64];
    float mx = -1e30f;
    for (int m = 0; m < 64; ++m) {
        float acc = 0.f;
#pragma unroll
        for (int c = 0; c < 16; ++c) acc += qv[c] * ks[c][m];
        acc *= SCALE;
        s[m] = acc;
        mx = fmaxf(mx, acc);
    }
    float sum = 0.f;
    for (int m = 0; m < 64; ++m) {
        s[m] = __expf(s[m] - mx);
        sum += s[m];
    }
    float inv = 1.f / sum;
    u16* dst = xxbf + (((size_t)(b * 2 + branch)) * 64 + n) * 512 + h * 64;
    for (int d = 0; d < 64; ++d) {
        float acc = 0.f;
#pragma unroll 8
        for (int m = 0; m < 64; ++m) acc += s[m] * vs[d][m];
        dst[d] = f2bf(fmaxf(acc * inv, 0.f));
    }
}

// -------- K6: post cbn via MFMA. per (o-half, b, branch): M=64(n) N=256(o) K=512.
// dst[b][n][o] fp32 (o contiguous).
__global__ __launch_bounds__(256) void post_gemm(
    const u16* __restrict__ xxbf, const u16* __restrict__ wrb, const u16* __restrict__ wcb,
    const float* __restrict__ s_row, const float* __restrict__ b_row,
    const float* __restrict__ s_col, const float* __restrict__ b_col,
    float* __restrict__ xr2, float* __restrict__ xc2) {
    __shared__ u16 ldsA[64 * 32];
    __shared__ u16 ldsB[256 * 32];
    int o0 = blockIdx.x * 256;
    int b = blockIdx.y;
    int branch = blockIdx.z;
    const u16* A = xxbf + ((size_t)(b * 2 + branch)) * 64 * 512;
    const u16* W = branch ? wcb : wrb;
    const float* ss = branch ? s_col : s_row;
    const float* bb = branch ? b_col : b_row;
    float* dst = (branch ? xc2 : xr2) + (size_t)b * 32768;

    f32x4 acc[4][4];
#pragma unroll
    for (int i = 0; i < 4; ++i)
#pragma unroll
        for (int j = 0; j < 4; ++j) acc[i][j] = (f32x4){0.f, 0.f, 0.f, 0.f};

    int t = threadIdx.x, w = t >> 6, lane = t & 63;
    int ks = (t & 3) * 8;
    const u16* gA = A + (size_t)(t >> 2) * 512 + ks;
    const u16* gB = W + (size_t)(o0 + (t >> 2)) * 512 + ks;
    u16* lA = ldsA + (t >> 2) * 32 + ks;
    u16* lB = ldsB + (t >> 2) * 32 + ks;
    const u16* fA = ldsA + (lane & 15) * 32 + ((lane >> 4) * 8);
    const u16* fB = ldsB + (w * 64 + (lane & 15)) * 32 + ((lane >> 4) * 8);

    for (int k0 = 0; k0 < 512; k0 += 32) {
        if (k0) __syncthreads();
        gload16(gA + k0, lA);
#pragma unroll
        for (int r = 0; r < 4; ++r)
            gload16(gB + k0 + (size_t)r * 64 * 512, lB + r * 64 * 32);
        __syncthreads();
        short8 a[4], bfr[4];
#pragma unroll
        for (int i = 0; i < 4; ++i) a[i] = *(const short8*)(fA + i * 16 * 32);
#pragma unroll
        for (int j = 0; j < 4; ++j) bfr[j] = *(const short8*)(fB + j * 16 * 32);
#pragma unroll
        for (int i = 0; i < 4; ++i)
#pragma unroll
            for (int j = 0; j < 4; ++j)
                acc[i][j] = __builtin_amdgcn_mfma_f32_16x16x32_bf16(a[i], bfr[j], acc[i][j], 0, 0, 0);
    }

    int quad = lane >> 4, cn = lane & 15;
#pragma unroll
    for (int i = 0; i < 4; ++i)
#pragma unroll
        for (int j = 0; j < 4; ++j) {
            int o = o0 + w * 64 + j * 16 + cn;
            float sv_ = ss[o], bv_ = bb[o];
#pragma unroll
            for (int r = 0; r < 4; ++r) {
                int n = i * 16 + quad * 4 + r;
                dst[n * 512 + o] = acc[i][j][r] * sv_ + bv_;
            }
        }
}

// ------------------------------------------------------------- MFMA GEMM mainloop
// D[o][p] = sum_k W[o][k] * X[p][k], 128x128 tile, BK=32, 4 waves (2x2 of 64x64).
__device__ __forceinline__ void gemm_mainloop(
    const u16* __restrict__ W, const u16* __restrict__ X, int K,
    int o0, size_t prow0, u16* ldsA, u16* ldsB, f32x4 (&acc)[4][4]) {
    int t = threadIdx.x;
    int w = t >> 6, lane = t & 63;
    int sr = (w << 5) + (lane >> 2);
    int ks = (lane & 3) * 8;
    const u16* gA = W + (size_t)(o0 + sr) * K + ks;
    const u16* gB = X + (prow0 + sr) * K + ks;
    u16* lA = ldsA + sr * 32 + ks;
    u16* lB = ldsB + sr * 32 + ks;
    int wo = (w >> 1) * 64, wp = (w & 1) * 64;
    const u16* fA = ldsA + (wo + (lane & 15)) * 32 + ((lane >> 4) * 8);
    const u16* fB = ldsB + (wp + (lane & 15)) * 32 + ((lane >> 4) * 8);

    for (int k0 = 0; k0 < K; k0 += 32) {
        if (k0) __syncthreads();
        gload16(gA + k0, lA);
        gload16(gA + k0 + (size_t)16 * K, lA + 16 * 32);
        gload16(gB + k0, lB);
        gload16(gB + k0 + (size_t)16 * K, lB + 16 * 32);
        __syncthreads();
        short8 a[4], b[4];
#pragma unroll
        for (int i = 0; i < 4; ++i) a[i] = *(const short8*)(fA + i * 16 * 32);
#pragma unroll
        for (int j = 0; j < 4; ++j) b[j] = *(const short8*)(fB + j * 16 * 32);
#pragma unroll
        for (int i = 0; i < 4; ++i)
#pragma unroll
            for (int j = 0; j < 4; ++j)
                acc[i][j] = __builtin_amdgcn_mfma_f32_16x16x32_bf16(a[i], b[j], acc[i][j], 0, 0, 0);
    }
}

// ------------------------------------- G1: sc = cbn(x, w_sc)  -> scb bf16 [p][256]
__global__ __launch_bounds__(256) void gemm_sc(
    const u16* __restrict__ Wb, const u16* __restrict__ X,
    const float* __restrict__ s, const float* __restrict__ bb, u16* __restrict__ outb) {
    __shared__ u16 ldsA[128 * 32];
    __shared__ u16 ldsB[128 * 32];
    f32x4 acc[4][4];
#pragma unroll
    for (int i = 0; i < 4; ++i)
#pragma unroll
        for (int j = 0; j < 4; ++j) acc[i][j] = (f32x4){0.f, 0.f, 0.f, 0.f};
    int o0 = blockIdx.x * 128;
    size_t prow0 = (size_t)blockIdx.y * 128;
    gemm_mainloop(Wb, X, 256, o0, prow0, ldsA, ldsB, acc);

    int lane = threadIdx.x & 63, w = threadIdx.x >> 6;
    int wo = (w >> 1) * 64, wp = (w & 1) * 64;
    int quad = lane >> 4, cn = lane & 15;
#pragma unroll
    for (int i = 0; i < 4; ++i) {
        int ob = o0 + wo + i * 16 + quad * 4;
        f32x4 s4 = *(const f32x4*)&s[ob];
        f32x4 b4 = *(const f32x4*)&bb[ob];
#pragma unroll
        for (int j = 0; j < 4; ++j) {
            size_t p = prow0 + wp + j * 16 + cn;
            ushort4 o4;
            o4.x = f2bf(acc[i][j][0] * s4[0] + b4[0]);
            o4.y = f2bf(acc[i][j][1] * s4[1] + b4[1]);
            o4.z = f2bf(acc[i][j][2] * s4[2] + b4[2]);
            o4.w = f2bf(acc[i][j][3] * s4[3] + b4[3]);
            *(ushort4*)&outb[p * 256 + ob] = o4;
        }
    }
}

// ------------- G2: abuf = relu(cbn(x,wv) + xr2 + xc2) -> bf16 [p][512]
__global__ __launch_bounds__(256) void gemm_v(
    const u16* __restrict__ Wb, const u16* __restrict__ X,
    const float* __restrict__ s, const float* __restrict__ bb,
    const float* __restrict__ xr2, const float* __restrict__ xc2, u16* __restrict__ outb) {
    __shared__ u16 ldsA[128 * 32];
    __shared__ u16 ldsB[128 * 32];
    f32x4 acc[4][4];
#pragma unroll
    for (int i = 0; i < 4; ++i)
#pragma unroll
        for (int j = 0; j < 4; ++j) acc[i][j] = (f32x4){0.f, 0.f, 0.f, 0.f};
    int o0 = blockIdx.x * 128;
    size_t prow0 = (size_t)blockIdx.y * 128;
    gemm_mainloop(Wb, X, 256, o0, prow0, ldsA, ldsB, acc);

    int lane = threadIdx.x & 63, w = threadIdx.x >> 6;
    int wo = (w >> 1) * 64, wp = (w & 1) * 64;
    int quad = lane >> 4, cn = lane & 15;
#pragma unroll
    for (int i = 0; i < 4; ++i) {
        int ob = o0 + wo + i * 16 + quad * 4;
        f32x4 s4 = *(const f32x4*)&s[ob];
        f32x4 b4 = *(const f32x4*)&bb[ob];
#pragma unroll
        for (int j = 0; j < 4; ++j) {
            size_t p = prow0 + wp + j * 16 + cn;
            int bi = (int)(p >> 12), hh = (int)((p >> 6) & 63), ww = (int)(p & 63);
            f32x4 ra = *(const f32x4*)&xr2[(size_t)bi * 32768 + hh * 512 + ob];
            f32x4 ca = *(const f32x4*)&xc2[(size_t)bi * 32768 + ww * 512 + ob];
            ushort4 o4;
            o4.x = f2bf(fmaxf(acc[i][j][0] * s4[0] + b4[0] + ra[0] + ca[0], 0.f));
            o4.y = f2bf(fmaxf(acc[i][j][1] * s4[1] + b4[1] + ra[1] + ca[1], 0.f));
            o4.z = f2bf(fmaxf(acc[i][j][2] * s4[2] + b4[2] + ra[2] + ca[2], 0.f));
            o4.w = f2bf(fmaxf(acc[i][j][3] * s4[3] + b4[3] + ra[3] + ca[3], 0.f));
            *(ushort4*)&outb[p * 512 + ob] = o4;
        }
    }
}

// ------------- G3: gate = h_sigmoid(cbn(dwout, w_pw)) -> bf16 [p][256]
__global__ __launch_bounds__(256) void gemm_pw(
    const u16* __restrict__ Wb, const u16* __restrict__ X,
    const float* __restrict__ s, const float* __restrict__ bb, u16* __restrict__ outb) {
    __shared__ u16 ldsA[128 * 32];
    __shared__ u16 ldsB[128 * 32];
    f32x4 acc[4][4];
#pragma unroll
    for (int i = 0; i < 4; ++i)
#pragma unroll
        for (int j = 0; j < 4; ++j) acc[i][j] = (f32x4){0.f, 0.f, 0.f, 0.f};
    int o0 = blockIdx.x * 128;
    size_t prow0 = (size_t)blockIdx.y * 128;
    gemm_mainloop(Wb, X, 256, o0, prow0, ldsA, ldsB, acc);

    int lane = threadIdx.x & 63, w = threadIdx.x >> 6;
    int wo = (w >> 1) * 64, wp = (w & 1) * 64;
    int quad = lane >> 4, cn = lane & 15;
#pragma unroll
    for (int i = 0; i < 4; ++i) {
        int ob = o0 + wo + i * 16 + quad * 4;
        f32x4 s4 = *(const f32x4*)&s[ob];
        f32x4 b4 = *(const f32x4*)&bb[ob];
#pragma unroll
        for (int j = 0; j < 4; ++j) {
            size_t p = prow0 + wp + j * 16 + cn;
            ushort4 o4;
            o4.x = f2bf(fminf(fmaxf(acc[i][j][0] * s4[0] + b4[0] + 3.f, 0.f), 6.f) * (1.f / 6.f));
            o4.y = f2bf(fminf(fmaxf(acc[i][j][1] * s4[1] + b4[1] + 3.f, 0.f), 6.f) * (1.f / 6.f));
            o4.z = f2bf(fminf(fmaxf(acc[i][j][2] * s4[2] + b4[2] + 3.f, 0.f), 6.f) * (1.f / 6.f));
            o4.w = f2bf(fminf(fmaxf(acc[i][j][3] * s4[3] + b4[3] + 3.f, 0.f), 6.f) * (1.f / 6.f));
            *(ushort4*)&outb[p * 256 + ob] = o4;
        }
    }
}

// ------------- G4: out[b][o][p] = gate[p][o] * cbn(abuf, w_proj)   (K=512, fp32 out)
__global__ __launch_bounds__(256) void gemm_proj(
    const u16* __restrict__ Wb, const u16* __restrict__ X,
    const float* __restrict__ s, const float* __restrict__ bb,
    const u16* __restrict__ gate, float* __restrict__ out) {
    __shared__ u16 ldsA[128 * 32];
    __shared__ u16 ldsB[128 * 32];
    f32x4 acc[4][4];
#pragma unroll
    for (int i = 0; i < 4; ++i)
#pragma unroll
        for (int j = 0; j < 4; ++j) acc[i][j] = (f32x4){0.f, 0.f, 0.f, 0.f};
    int o0 = blockIdx.x * 128;
    size_t prow0 = (size_t)blockIdx.y * 128;
    gemm_mainloop(Wb, X, 512, o0, prow0, ldsA, ldsB, acc);

    int lane = threadIdx.x & 63, w = threadIdx.x >> 6;
    int wo = (w >> 1) * 64, wp = (w & 1) * 64;
    int quad = lane >> 4, cn = lane & 15;
#pragma unroll
    for (int i = 0; i < 4; ++i) {
        int ob = o0 + wo + i * 16 + quad * 4;
        f32x4 s4 = *(const f32x4*)&s[ob];
        f32x4 b4 = *(const f32x4*)&bb[ob];
#pragma unroll
        for (int j = 0; j < 4; ++j) {
            size_t p = prow0 + wp + j * 16 + cn;
            int bi = (int)(p >> 12), pl = (int)(p & 4095);
            ushort4 gv = *(const ushort4*)&gate[p * 256 + ob];
            float* op = out + (size_t)bi * 1048576 + (size_t)ob * 4096 + pl;
            op[0 * 4096] = bf2f(gv.x) * (acc[i][j][0] * s4[0] + b4[0]);
            op[1 * 4096] = bf2f(gv.y) * (acc[i][j][1] * s4[1] + b4[1]);
            op[2 * 4096] = bf2f(gv.z) * (acc[i][j][2] * s4[2] + b4[2]);
            op[3 * 4096] = bf2f(gv.w) * (acc[i][j][3] * s4[3] + b4[3]);
        }
    }
}

// --------------- K7: depthwise 3x3 + affine + relu, [p][c], 8 channels/thread
__global__ __launch_bounds__(256) void dw_kernel(
    const u16* __restrict__ sc, const float* __restrict__ wdwT,
    const float* __restrict__ sdw, const float* __restrict__ bdw, u16* __restrict__ dwout) {
    int t = blockIdx.x * 256 + threadIdx.x;  // PTOT * 32
    int cg = (t & 31) * 8;
    size_t p = (size_t)(t >> 5);
    int h = (int)((p >> 6) & 63), w_ = (int)(p & 63);
    float acc[8] = {0.f, 0.f, 0.f, 0.f, 0.f, 0.f, 0.f, 0.f};
#pragma unroll
    for (int ky = 0; ky < 3; ++ky) {
        int hh = h + ky - 1;
        if (hh < 0 || hh > 63) continue;
#pragma unroll
        for (int kx = 0; kx < 3; ++kx) {
            int wx = w_ + kx - 1;
            if (wx < 0 || wx > 63) continue;
            size_t pp = (size_t)((long long)p + (ky - 1) * 64 + (kx - 1));
            short8 v = *(const short8*)&sc[pp * 256 + cg];
            const float* wt = &wdwT[(ky * 3 + kx) * 256 + cg];
            f32x4 w0 = *(const f32x4*)wt;
            f32x4 w1 = *(const f32x4*)(wt + 4);
            acc[0] += w0[0] * bf2f((u16)v[0]); acc[1] += w0[1] * bf2f((u16)v[1]);
            acc[2] += w0[2] * bf2f((u16)v[2]); acc[3] += w0[3] * bf2f((u16)v[3]);
            acc[4] += w1[0] * bf2f((u16)v[4]); acc[5] += w1[1] * bf2f((u16)v[5]);
            acc[6] += w1[2] * bf2f((u16)v[6]); acc[7] += w1[3] * bf2f((u16)v[7]);
        }
    }
    f32x4 s0 = *(const f32x4*)&sdw[cg], s1 = *(const f32x4*)&sdw[cg + 4];
    f32x4 b0 = *(const f32x4*)&bdw[cg], b1 = *(const f32x4*)&bdw[cg + 4];
    short8 o;
    o[0] = (short)f2bf(fmaxf(acc[0] * s0[0] + b0[0], 0.f));
    o[1] = (short)f2bf(fmaxf(acc[1] * s0[1] + b0[1], 0.f));
    o[2] = (short)f2bf(fmaxf(acc[2] * s0[2] + b0[2], 0.f));
    o[3] = (short)f2bf(fmaxf(acc[3] * s0[3] + b0[3], 0.f));
    o[4] = (short)f2bf(fmaxf(acc[4] * s1[0] + b1[0], 0.f));
    o[5] = (short)f2bf(fmaxf(acc[5] * s1[1] + b1[1], 0.f));
    o[6] = (short)f2bf(fmaxf(acc[6] * s1[2] + b1[2], 0.f));
    o[7] = (short)f2bf(fmaxf(acc[7] * s1[3] + b1[3], 0.f));
    *(short8*)&dwout[p * 256 + cg] = o;
}

extern "C" void kernel_launch(void* const* d_in, const int* in_sizes, int n_in,
                              void* d_out, int out_size, void* d_ws, size_t ws_size,
                              hipStream_t stream) {
    const float* x = (const float*)d_in[0];
    const float* wq = (const float*)d_in[1];
    const float* sq = (const float*)d_in[2];
    const float* bq = (const float*)d_in[3];
    const float* wk = (const float*)d_in[4];
    const float* sk = (const float*)d_in[5];
    const float* bk = (const float*)d_in[6];
    const float* wv = (const float*)d_in[7];
    const float* sv = (const float*)d_in[8];
    const float* bv = (const float*)d_in[9];
    const float* posrq = (const float*)d_in[10];
    const float* posrk = (const float*)d_in[11];
    const float* poscq = (const float*)d_in[12];
    const float* posck = (const float*)d_in[13];
    const float* w_row = (const float*)d_in[14];
    const float* s_row = (const float*)d_in[15];
    const float* b_row = (const float*)d_in[16];
    const float* w_col = (const float*)d_in[17];
    const float* s_col = (const float*)d_in[18];
    const float* b_col = (const float*)d_in[19];
    const float* w_proj = (const float*)d_in[20];
    const float* s_proj = (const float*)d_in[21];
    const float* b_proj = (const float*)d_in[22];
    const float* w_sc = (const float*)d_in[23];
    const float* s_sc = (const float*)d_in[24];
    const float* b_sc = (const float*)d_in[25];
    const float* w_dw = (const float*)d_in[26];
    const float* s_dw = (const float*)d_in[27];
    const float* b_dw = (const float*)d_in[28];
    const float* w_pw = (const float*)d_in[29];
    const float* s_pw = (const float*)d_in[30];
    const float* b_pw = (const float*)d_in[31];
    float* out = (float*)d_out;

    float* fws = (float*)d_ws;
    float* xrowT = fws;                  // [b][n][256]
    float* xcolT = xrowT + 262144;
    float* qrow = xcolT + 262144;        // [b][c][n]
    float* krow = qrow + 131072;
    float* qcol = krow + 131072;
    float* kcol = qcol + 131072;
    float* vrow = kcol + 131072;
    float* vcol = vrow + 524288;
    float* xr2  = vcol + 524288;         // [b][n][512] fp32
    float* xc2  = xr2 + 524288;
    float* wdwT = xc2 + 524288;          // [9][256]
    u16* xbf    = (u16*)(wdwT + 2304);            // [65536][256]
    u16* wvb    = xbf + (size_t)PTOT * 256;       // [512][256]
    u16* wscb   = wvb + 131072;                   // [256][256]
    u16* wprojb = wscb + 65536;                   // [256][512]
    u16* wpwb   = wprojb + 131072;                // [256][256]
    u16* wrb    = wpwb + 65536;                   // [512][512]
    u16* wcb    = wrb + 262144;                   // [512][512]
    u16* xxbf   = wcb + 262144;                   // [b][br][64][512]
    u16* scb    = xxbf + 1048576;                 // [65536][256]
    u16* dwb    = scb + (size_t)PTOT * 256;       // [65536][256]
    u16* abuf   = dwb + (size_t)PTOT * 256;       // [65536][512]
    u16* gate   = scb;                            // alias: sc dead after dw_kernel

    mean_kernel<<<dim3(Bn * Cc), 256, 0, stream>>>(x, xrowT, xcolT);
    xpose_kernel<<<dim3(64, 4, Bn), 256, 0, stream>>>(x, xbf);
    wconv_kernel<<<dim3(3584), 256, 0, stream>>>(
        wv, w_sc, w_proj, w_pw, w_row, w_col, w_dw,
        wvb, wscb, wprojb, wpwb, wrb, wcb, wdwT);
    emb_kernel<<<dim3(3072, 2), 256, 0, stream>>>(
        xrowT, xcolT, wq, sq, bq, wk, sk, bk, wv, sv, bv,
        posrq, posrk, poscq, posck, qrow, krow, vrow, qcol, kcol, vcol);
    attn_kernel<<<dim3(128, 2), 64, 0, stream>>>(qrow, krow, vrow, qcol, kcol, vcol, xxbf);
    post_gemm<<<dim3(2, Bn, 2), 256, 0, stream>>>(
        xxbf, wrb, wcb, s_row, b_row, s_col, b_col, xr2, xc2);
    gemm_sc<<<dim3(2, 512), 256, 0, stream>>>(wscb, xbf, s_sc, b_sc, scb);
    dw_kernel<<<dim3(8192), 256, 0, stream>>>(scb, wdwT, s_dw, b_dw, dwb);
    gemm_v<<<dim3(4, 512), 256, 0, stream>>>(wvb, xbf, sv, bv, xr2, xc2, abuf);
    gemm_pw<<<dim3(2, 512), 256, 0, stream>>>(wpwb, dwb, s_pw, b_pw, gate);
    gemm_proj<<<dim3(2, 512), 256, 0, stream>>>(wprojb, abuf, s_proj, b_proj, gate, out);
}

// Round 5
// 523.995 us; speedup vs baseline: 7.6621x; 1.3689x over previous
//
#include <hip/hip_runtime.h>
#include <math.h>

typedef unsigned short u16;
typedef unsigned int u32;
typedef short short8 __attribute__((ext_vector_type(8)));
typedef float f32x4 __attribute__((ext_vector_type(4)));

#define Bn 16
#define Cc 256
#define Pp 4096
#define DHc 512
#define PTOT 65536   // Bn * Pp
#define SCALE 0.25f

__device__ __forceinline__ float bf2f(u16 u) {
    return __uint_as_float(((u32)u) << 16);
}
__device__ __forceinline__ u16 f2bf(float f) {
    u32 u = __float_as_uint(f);
    u32 lsb = (u >> 16) & 1u;
    u += 0x7fffu + lsb;  // round-to-nearest-even
    return (u16)(u >> 16);
}

// global -> LDS direct copy, 16 bytes per lane (LDS dest must be base + lane*16).
__device__ __forceinline__ void gload16(const u16* g, u16* l) {
    __builtin_amdgcn_global_load_lds(
        (const __attribute__((address_space(1))) void*)(uintptr_t)g,
        (__attribute__((address_space(3))) void*)(u32)(uintptr_t)l,
        16, 0, 0);
}

// ---------------- K1: means -> bf16 xmb [2048][256]; rows 0..1023 = (b,h) row-branch,
// rows 1024..2047 = (b,w) col-branch.
__global__ __launch_bounds__(256) void mean_kernel(
    const float* __restrict__ x, u16* __restrict__ xmb) {
    __shared__ float plane[64][65];
    int bc = blockIdx.x;
    int b = bc >> 8, c = bc & 255;
    const float* xp = x + (size_t)bc * Pp;
    int tid = threadIdx.x;
#pragma unroll
    for (int k = 0; k < 16; ++k) {
        int idx = tid + k * 256;
        plane[idx >> 6][idx & 63] = xp[idx];
    }
    __syncthreads();
    if (tid < 64) {
        float s = 0.f;
#pragma unroll
        for (int w = 0; w < 64; ++w) s += plane[tid][w];
        xmb[((size_t)b * 64 + tid) * 256 + c] = f2bf(s * (1.f / 64.f));
    } else if (tid < 128) {
        int w = tid - 64;
        float s = 0.f;
#pragma unroll
        for (int h = 0; h < 64; ++h) s += plane[h][w];
        xmb[((size_t)1024 + b * 64 + w) * 256 + c] = f2bf(s * (1.f / 64.f));
    }
}

// --------------------- K2: transpose x [b][c][p] -> xbf [b*P+p][c] bf16
__global__ __launch_bounds__(256) void xpose_kernel(
    const float* __restrict__ x, u16* __restrict__ xbf) {
    __shared__ float tile[64][65];
    int pb = blockIdx.x;
    int cb = blockIdx.y;
    int b = blockIdx.z;
    int t = threadIdx.x;
    int p_l = t & 63, c_q = t >> 6;
    const float* xp = x + ((size_t)b * Cc + cb * 64) * Pp + pb * 64;
#pragma unroll
    for (int rr = 0; rr < 16; ++rr) {
        int c_l = rr * 4 + c_q;
        tile[p_l][c_l] = xp[(size_t)c_l * Pp + p_l];
    }
    __syncthreads();
    int c_l2 = t & 63, p_q = t >> 6;
    u16* dst = xbf + ((size_t)b * Pp + pb * 64) * Cc + cb * 64;
#pragma unroll
    for (int rr = 0; rr < 16; ++rr) {
        int p_l2 = rr * 4 + p_q;
        dst[(size_t)p_l2 * Cc + c_l2] = f2bf(tile[p_l2][c_l2]);
    }
}

// -------------- K3: weights fp32 -> bf16; wq/wk/wv stacked into wqkvb [768][256]
__global__ __launch_bounds__(256) void wconv_kernel(
    const float* __restrict__ wq, const float* __restrict__ wk, const float* __restrict__ wv,
    const float* __restrict__ wsc, const float* __restrict__ wproj, const float* __restrict__ wpw,
    const float* __restrict__ wrow, const float* __restrict__ wcol,
    const float* __restrict__ wdw,
    u16* __restrict__ wqkvb, u16* __restrict__ wscb,
    u16* __restrict__ wprojb, u16* __restrict__ wpwb,
    u16* __restrict__ wrb, u16* __restrict__ wcb, float* __restrict__ wdwT) {
    int t = blockIdx.x * 256 + threadIdx.x;  // 983040 total
    if (t < 2304) wdwT[(t % 9) * 256 + (t / 9)] = wdw[t];
    if (t < 32768) wqkvb[t] = f2bf(wq[t]);
    else if (t < 65536) wqkvb[t] = f2bf(wk[t - 32768]);
    else if (t < 196608) wqkvb[t] = f2bf(wv[t - 65536]);
    else if (t < 262144) wscb[t - 196608] = f2bf(wsc[t - 196608]);
    else if (t < 393216) wprojb[t - 262144] = f2bf(wproj[t - 262144]);
    else if (t < 458752) wpwb[t - 393216] = f2bf(wpw[t - 393216]);
    else if (t < 720896) wrb[t - 458752] = f2bf(wrow[t - 458752]);
    else wcb[t - 720896] = f2bf(wcol[t - 720896]);
}

// ------------------------------------------------------------- MFMA GEMM mainloop
// D[o][p] = sum_k W[o][k] * X[p][k], 128x128 tile, BK=32, 4 waves (2x2 of 64x64).
__device__ __forceinline__ void gemm_mainloop(
    const u16* __restrict__ W, const u16* __restrict__ X, int K,
    int o0, size_t prow0, u16* ldsA, u16* ldsB, f32x4 (&acc)[4][4]) {
    int t = threadIdx.x;
    int w = t >> 6, lane = t & 63;
    int sr = (w << 5) + (lane >> 2);
    int ks = (lane & 3) * 8;
    const u16* gA = W + (size_t)(o0 + sr) * K + ks;
    const u16* gB = X + (prow0 + sr) * K + ks;
    u16* lA = ldsA + sr * 32 + ks;
    u16* lB = ldsB + sr * 32 + ks;
    int wo = (w >> 1) * 64, wp = (w & 1) * 64;
    const u16* fA = ldsA + (wo + (lane & 15)) * 32 + ((lane >> 4) * 8);
    const u16* fB = ldsB + (wp + (lane & 15)) * 32 + ((lane >> 4) * 8);

    for (int k0 = 0; k0 < K; k0 += 32) {
        if (k0) __syncthreads();
        gload16(gA + k0, lA);
        gload16(gA + k0 + (size_t)16 * K, lA + 16 * 32);
        gload16(gB + k0, lB);
        gload16(gB + k0 + (size_t)16 * K, lB + 16 * 32);
        __syncthreads();
        short8 a[4], b[4];
#pragma unroll
        for (int i = 0; i < 4; ++i) a[i] = *(const short8*)(fA + i * 16 * 32);
#pragma unroll
        for (int j = 0; j < 4; ++j) b[j] = *(const short8*)(fB + j * 16 * 32);
#pragma unroll
        for (int i = 0; i < 4; ++i)
#pragma unroll
            for (int j = 0; j < 4; ++j)
                acc[i][j] = __builtin_amdgcn_mfma_f32_16x16x32_bf16(a[i], b[j], acc[i][j], 0, 0, 0);
    }
}

// ---------- K4: q/k/v embeddings as one GEMM: [768]x[2048 rows]xK=256.
// Epilogue: scale/bias (+pos interp for q/k), scatter fp32 to [b][c][n] layouts.
__global__ __launch_bounds__(256) void gemm_qkv(
    const u16* __restrict__ Wb, const u16* __restrict__ X,
    const float* __restrict__ sq, const float* __restrict__ bq,
    const float* __restrict__ sk, const float* __restrict__ bk,
    const float* __restrict__ sv, const float* __restrict__ bv,
    const float* __restrict__ posrq, const float* __restrict__ posrk,
    const float* __restrict__ poscq, const float* __restrict__ posck,
    float* __restrict__ qrow, float* __restrict__ krow, float* __restrict__ vrow,
    float* __restrict__ qcol, float* __restrict__ kcol, float* __restrict__ vcol) {
    __shared__ u16 ldsA[128 * 32];
    __shared__ u16 ldsB[128 * 32];
    f32x4 acc[4][4];
#pragma unroll
    for (int i = 0; i < 4; ++i)
#pragma unroll
        for (int j = 0; j < 4; ++j) acc[i][j] = (f32x4){0.f, 0.f, 0.f, 0.f};
    int o0 = blockIdx.x * 128;          // 0..5
    size_t prow0 = (size_t)blockIdx.y * 128;  // 0..15
    gemm_mainloop(Wb, X, 256, o0, prow0, ldsA, ldsB, acc);

    int lane = threadIdx.x & 63, w = threadIdx.x >> 6;
    int wo = (w >> 1) * 64, wp = (w & 1) * 64;
    int quad = lane >> 4, cn = lane & 15;
#pragma unroll
    for (int j = 0; j < 4; ++j) {
        int p = (int)prow0 + wp + j * 16 + cn;
        int branch = p >> 10, loc = p & 1023;
        int b = loc >> 6, n = loc & 63;
        float coords = 0.25f * (float)n - 0.375f;
        coords = fminf(fmaxf(coords, 0.f), 15.f);
        int lo = (int)floorf(coords);
        int hi = min(lo + 1, 15);
        float tt = coords - (float)lo;
#pragma unroll
        for (int i = 0; i < 4; ++i) {
            int o = o0 + wo + i * 16 + quad * 4;
            if (o < 128) {
                const float* pos = branch ? poscq : posrq;
                float* dst = branch ? qcol : qrow;
#pragma unroll
                for (int r = 0; r < 4; ++r) {
                    int c = o + r;
                    float pv = pos[c * 16 + lo] * (1.f - tt) + pos[c * 16 + hi] * tt;
                    dst[b * 8192 + c * 64 + n] = acc[i][j][r] * sq[c] + bq[c] + pv;
                }
            } else if (o < 256) {
                const float* pos = branch ? posck : posrk;
                float* dst = branch ? kcol : krow;
#pragma unroll
                for (int r = 0; r < 4; ++r) {
                    int c = o - 128 + r;
                    float pv = pos[c * 16 + lo] * (1.f - tt) + pos[c * 16 + hi] * tt;
                    dst[b * 8192 + c * 64 + n] = acc[i][j][r] * sk[c] + bk[c] + pv;
                }
            } else {
                float* dst = branch ? vcol : vrow;
#pragma unroll
                for (int r = 0; r < 4; ++r) {
                    int c = o - 256 + r;
                    dst[b * 32768 + c * 64 + n] = acc[i][j][r] * sv[c] + bv[c];
                }
            }
        }
    }
}

// ---------------- K5: axial attention; emits relu(xx) bf16 transposed [b][br][n][i]
__global__ __launch_bounds__(64) void attn_kernel(
    const float* __restrict__ qr, const float* __restrict__ kr, const float* __restrict__ vr,
    const float* __restrict__ qc, const float* __restrict__ kc, const float* __restrict__ vc,
    u16* __restrict__ xxbf) {
    int branch = blockIdx.y;
    const float* q = branch ? qc : qr;
    const float* k = branch ? kc : kr;
    const float* v = branch ? vc : vr;
    int bh = blockIdx.x;
    int b = bh >> 3, h = bh & 7;
    __shared__ float qs[16][64], ks[16][64], vs[64][64];
    int n = threadIdx.x;
#pragma unroll
    for (int c = 0; c < 16; ++c) {
        qs[c][n] = q[b * 8192 + (h * 16 + c) * 64 + n];
        ks[c][n] = k[b * 8192 + (h * 16 + c) * 64 + n];
    }
#pragma unroll
    for (int d = 0; d < 64; ++d)
        vs[d][n] = v[b * 32768 + (h * 64 + d) * 64 + n];
    __syncthreads();

    float qv[16];
#pragma unroll
    for (int c = 0; c < 16; ++c) qv[c] = qs[c][n];

    float s[64];
    float mx = -1e30f;
    for (int m = 0; m < 64; ++m) {
        float acc = 0.f;
#pragma unroll
        for (int c = 0; c < 16; ++c) acc += qv[c] * ks[c][m];
        acc *= SCALE;
        s[m] = acc;
        mx = fmaxf(mx, acc);
    }
    float sum = 0.f;
    for (int m = 0; m < 64; ++m) {
        s[m] = __expf(s[m] - mx);
        sum += s[m];
    }
    float inv = 1.f / sum;
    u16* dst = xxbf + (((size_t)(b * 2 + branch)) * 64 + n) * 512 + h * 64;
    for (int d = 0; d < 64; ++d) {
        float acc = 0.f;
#pragma unroll 8
        for (int m = 0; m < 64; ++m) acc += s[m] * vs[d][m];
        dst[d] = f2bf(fmaxf(acc * inv, 0.f));
    }
}

// -------- K6: post cbn via MFMA. per (o-half, b, branch): M=64(n) N=256(o) K=512.
__global__ __launch_bounds__(256) void post_gemm(
    const u16* __restrict__ xxbf, const u16* __restrict__ wrb, const u16* __restrict__ wcb,
    const float* __restrict__ s_row, const float* __restrict__ b_row,
    const float* __restrict__ s_col, const float* __restrict__ b_col,
    float* __restrict__ xr2, float* __restrict__ xc2) {
    __shared__ u16 ldsA[64 * 32];
    __shared__ u16 ldsB[256 * 32];
    int o0 = blockIdx.x * 256;
    int b = blockIdx.y;
    int branch = blockIdx.z;
    const u16* A = xxbf + ((size_t)(b * 2 + branch)) * 64 * 512;
    const u16* W = branch ? wcb : wrb;
    const float* ss = branch ? s_col : s_row;
    const float* bb = branch ? b_col : b_row;
    float* dst = (branch ? xc2 : xr2) + (size_t)b * 32768;

    f32x4 acc[4][4];
#pragma unroll
    for (int i = 0; i < 4; ++i)
#pragma unroll
        for (int j = 0; j < 4; ++j) acc[i][j] = (f32x4){0.f, 0.f, 0.f, 0.f};

    int t = threadIdx.x, w = t >> 6, lane = t & 63;
    int ks = (t & 3) * 8;
    const u16* gA = A + (size_t)(t >> 2) * 512 + ks;
    const u16* gB = W + (size_t)(o0 + (t >> 2)) * 512 + ks;
    u16* lA = ldsA + (t >> 2) * 32 + ks;
    u16* lB = ldsB + (t >> 2) * 32 + ks;
    const u16* fA = ldsA + (lane & 15) * 32 + ((lane >> 4) * 8);
    const u16* fB = ldsB + (w * 64 + (lane & 15)) * 32 + ((lane >> 4) * 8);

    for (int k0 = 0; k0 < 512; k0 += 32) {
        if (k0) __syncthreads();
        gload16(gA + k0, lA);
#pragma unroll
        for (int r = 0; r < 4; ++r)
            gload16(gB + k0 + (size_t)r * 64 * 512, lB + r * 64 * 32);
        __syncthreads();
        short8 a[4], bfr[4];
#pragma unroll
        for (int i = 0; i < 4; ++i) a[i] = *(const short8*)(fA + i * 16 * 32);
#pragma unroll
        for (int j = 0; j < 4; ++j) bfr[j] = *(const short8*)(fB + j * 16 * 32);
#pragma unroll
        for (int i = 0; i < 4; ++i)
#pragma unroll
            for (int j = 0; j < 4; ++j)
                acc[i][j] = __builtin_amdgcn_mfma_f32_16x16x32_bf16(a[i], bfr[j], acc[i][j], 0, 0, 0);
    }

    int quad = lane >> 4, cn = lane & 15;
#pragma unroll
    for (int i = 0; i < 4; ++i)
#pragma unroll
        for (int j = 0; j < 4; ++j) {
            int o = o0 + w * 64 + j * 16 + cn;
            float sv_ = ss[o], bv_ = bb[o];
#pragma unroll
            for (int r = 0; r < 4; ++r) {
                int n = i * 16 + quad * 4 + r;
                dst[n * 512 + o] = acc[i][j][r] * sv_ + bv_;
            }
        }
}

// ------------------------------------- G1: sc = cbn(x, w_sc)  -> scb bf16 [p][256]
__global__ __launch_bounds__(256) void gemm_sc(
    const u16* __restrict__ Wb, const u16* __restrict__ X,
    const float* __restrict__ s, const float* __restrict__ bb, u16* __restrict__ outb) {
    __shared__ u16 ldsA[128 * 32];
    __shared__ u16 ldsB[128 * 32];
    f32x4 acc[4][4];
#pragma unroll
    for (int i = 0; i < 4; ++i)
#pragma unroll
        for (int j = 0; j < 4; ++j) acc[i][j] = (f32x4){0.f, 0.f, 0.f, 0.f};
    int o0 = blockIdx.x * 128;
    size_t prow0 = (size_t)blockIdx.y * 128;
    gemm_mainloop(Wb, X, 256, o0, prow0, ldsA, ldsB, acc);

    int lane = threadIdx.x & 63, w = threadIdx.x >> 6;
    int wo = (w >> 1) * 64, wp = (w & 1) * 64;
    int quad = lane >> 4, cn = lane & 15;
#pragma unroll
    for (int i = 0; i < 4; ++i) {
        int ob = o0 + wo + i * 16 + quad * 4;
        f32x4 s4 = *(const f32x4*)&s[ob];
        f32x4 b4 = *(const f32x4*)&bb[ob];
#pragma unroll
        for (int j = 0; j < 4; ++j) {
            size_t p = prow0 + wp + j * 16 + cn;
            ushort4 o4;
            o4.x = f2bf(acc[i][j][0] * s4[0] + b4[0]);
            o4.y = f2bf(acc[i][j][1] * s4[1] + b4[1]);
            o4.z = f2bf(acc[i][j][2] * s4[2] + b4[2]);
            o4.w = f2bf(acc[i][j][3] * s4[3] + b4[3]);
            *(ushort4*)&outb[p * 256 + ob] = o4;
        }
    }
}

// ------------- G2: abuf = relu(cbn(x,wv) + xr2 + xc2) -> bf16 [p][512]
__global__ __launch_bounds__(256) void gemm_v(
    const u16* __restrict__ Wb, const u16* __restrict__ X,
    const float* __restrict__ s, const float* __restrict__ bb,
    const float* __restrict__ xr2, const float* __restrict__ xc2, u16* __restrict__ outb) {
    __shared__ u16 ldsA[128 * 32];
    __shared__ u16 ldsB[128 * 32];
    f32x4 acc[4][4];
#pragma unroll
    for (int i = 0; i < 4; ++i)
#pragma unroll
        for (int j = 0; j < 4; ++j) acc[i][j] = (f32x4){0.f, 0.f, 0.f, 0.f};
    int o0 = blockIdx.x * 128;
    size_t prow0 = (size_t)blockIdx.y * 128;
    gemm_mainloop(Wb, X, 256, o0, prow0, ldsA, ldsB, acc);

    int lane = threadIdx.x & 63, w = threadIdx.x >> 6;
    int wo = (w >> 1) * 64, wp = (w & 1) * 64;
    int quad = lane >> 4, cn = lane & 15;
#pragma unroll
    for (int i = 0; i < 4; ++i) {
        int ob = o0 + wo + i * 16 + quad * 4;
        f32x4 s4 = *(const f32x4*)&s[ob];
        f32x4 b4 = *(const f32x4*)&bb[ob];
#pragma unroll
        for (int j = 0; j < 4; ++j) {
            size_t p = prow0 + wp + j * 16 + cn;
            int bi = (int)(p >> 12), hh = (int)((p >> 6) & 63), ww = (int)(p & 63);
            f32x4 ra = *(const f32x4*)&xr2[(size_t)bi * 32768 + hh * 512 + ob];
            f32x4 ca = *(const f32x4*)&xc2[(size_t)bi * 32768 + ww * 512 + ob];
            ushort4 o4;
            o4.x = f2bf(fmaxf(acc[i][j][0] * s4[0] + b4[0] + ra[0] + ca[0], 0.f));
            o4.y = f2bf(fmaxf(acc[i][j][1] * s4[1] + b4[1] + ra[1] + ca[1], 0.f));
            o4.z = f2bf(fmaxf(acc[i][j][2] * s4[2] + b4[2] + ra[2] + ca[2], 0.f));
            o4.w = f2bf(fmaxf(acc[i][j][3] * s4[3] + b4[3] + ra[3] + ca[3], 0.f));
            *(ushort4*)&outb[p * 512 + ob] = o4;
        }
    }
}

// ------------- G3: gate = h_sigmoid(cbn(dwout, w_pw)) -> bf16 [p][256]
__global__ __launch_bounds__(256) void gemm_pw(
    const u16* __restrict__ Wb, const u16* __restrict__ X,
    const float* __restrict__ s, const float* __restrict__ bb, u16* __restrict__ outb) {
    __shared__ u16 ldsA[128 * 32];
    __shared__ u16 ldsB[128 * 32];
    f32x4 acc[4][4];
#pragma unroll
    for (int i = 0; i < 4; ++i)
#pragma unroll
        for (int j = 0; j < 4; ++j) acc[i][j] = (f32x4){0.f, 0.f, 0.f, 0.f};
    int o0 = blockIdx.x * 128;
    size_t prow0 = (size_t)blockIdx.y * 128;
    gemm_mainloop(Wb, X, 256, o0, prow0, ldsA, ldsB, acc);

    int lane = threadIdx.x & 63, w = threadIdx.x >> 6;
    int wo = (w >> 1) * 64, wp = (w & 1) * 64;
    int quad = lane >> 4, cn = lane & 15;
#pragma unroll
    for (int i = 0; i < 4; ++i) {
        int ob = o0 + wo + i * 16 + quad * 4;
        f32x4 s4 = *(const f32x4*)&s[ob];
        f32x4 b4 = *(const f32x4*)&bb[ob];
#pragma unroll
        for (int j = 0; j < 4; ++j) {
            size_t p = prow0 + wp + j * 16 + cn;
            ushort4 o4;
            o4.x = f2bf(fminf(fmaxf(acc[i][j][0] * s4[0] + b4[0] + 3.f, 0.f), 6.f) * (1.f / 6.f));
            o4.y = f2bf(fminf(fmaxf(acc[i][j][1] * s4[1] + b4[1] + 3.f, 0.f), 6.f) * (1.f / 6.f));
            o4.z = f2bf(fminf(fmaxf(acc[i][j][2] * s4[2] + b4[2] + 3.f, 0.f), 6.f) * (1.f / 6.f));
            o4.w = f2bf(fminf(fmaxf(acc[i][j][3] * s4[3] + b4[3] + 3.f, 0.f), 6.f) * (1.f / 6.f));
            *(ushort4*)&outb[p * 256 + ob] = o4;
        }
    }
}

// ------------- G4: out[b][o][p] = gate[p][o] * cbn(abuf, w_proj)   (K=512, fp32 out)
__global__ __launch_bounds__(256) void gemm_proj(
    const u16* __restrict__ Wb, const u16* __restrict__ X,
    const float* __restrict__ s, const float* __restrict__ bb,
    const u16* __restrict__ gate, float* __restrict__ out) {
    __shared__ u16 ldsA[128 * 32];
    __shared__ u16 ldsB[128 * 32];
    f32x4 acc[4][4];
#pragma unroll
    for (int i = 0; i < 4; ++i)
#pragma unroll
        for (int j = 0; j < 4; ++j) acc[i][j] = (f32x4){0.f, 0.f, 0.f, 0.f};
    int o0 = blockIdx.x * 128;
    size_t prow0 = (size_t)blockIdx.y * 128;
    gemm_mainloop(Wb, X, 512, o0, prow0, ldsA, ldsB, acc);

    int lane = threadIdx.x & 63, w = threadIdx.x >> 6;
    int wo = (w >> 1) * 64, wp = (w & 1) * 64;
    int quad = lane >> 4, cn = lane & 15;
#pragma unroll
    for (int i = 0; i < 4; ++i) {
        int ob = o0 + wo + i * 16 + quad * 4;
        f32x4 s4 = *(const f32x4*)&s[ob];
        f32x4 b4 = *(const f32x4*)&bb[ob];
#pragma unroll
        for (int j = 0; j < 4; ++j) {
            size_t p = prow0 + wp + j * 16 + cn;
            int bi = (int)(p >> 12), pl = (int)(p & 4095);
            ushort4 gv = *(const ushort4*)&gate[p * 256 + ob];
            float* op = out + (size_t)bi * 1048576 + (size_t)ob * 4096 + pl;
            op[0 * 4096] = bf2f(gv.x) * (acc[i][j][0] * s4[0] + b4[0]);
            op[1 * 4096] = bf2f(gv.y) * (acc[i][j][1] * s4[1] + b4[1]);
            op[2 * 4096] = bf2f(gv.z) * (acc[i][j][2] * s4[2] + b4[2]);
            op[3 * 4096] = bf2f(gv.w) * (acc[i][j][3] * s4[3] + b4[3]);
        }
    }
}

// --------------- K7: depthwise 3x3 + affine + relu, [p][c], 8 channels/thread
__global__ __launch_bounds__(256) void dw_kernel(
    const u16* __restrict__ sc, const float* __restrict__ wdwT,
    const float* __restrict__ sdw, const float* __restrict__ bdw, u16* __restrict__ dwout) {
    int t = blockIdx.x * 256 + threadIdx.x;  // PTOT * 32
    int cg = (t & 31) * 8;
    size_t p = (size_t)(t >> 5);
    int h = (int)((p >> 6) & 63), w_ = (int)(p & 63);
    float acc[8] = {0.f, 0.f, 0.f, 0.f, 0.f, 0.f, 0.f, 0.f};
#pragma unroll
    for (int ky = 0; ky < 3; ++ky) {
        int hh = h + ky - 1;
        if (hh < 0 || hh > 63) continue;
#pragma unroll
        for (int kx = 0; kx < 3; ++kx) {
            int wx = w_ + kx - 1;
            if (wx < 0 || wx > 63) continue;
            size_t pp = (size_t)((long long)p + (ky - 1) * 64 + (kx - 1));
            short8 v = *(const short8*)&sc[pp * 256 + cg];
            const float* wt = &wdwT[(ky * 3 + kx) * 256 + cg];
            f32x4 w0 = *(const f32x4*)wt;
            f32x4 w1 = *(const f32x4*)(wt + 4);
            acc[0] += w0[0] * bf2f((u16)v[0]); acc[1] += w0[1] * bf2f((u16)v[1]);
            acc[2] += w0[2] * bf2f((u16)v[2]); acc[3] += w0[3] * bf2f((u16)v[3]);
            acc[4] += w1[0] * bf2f((u16)v[4]); acc[5] += w1[1] * bf2f((u16)v[5]);
            acc[6] += w1[2] * bf2f((u16)v[6]); acc[7] += w1[3] * bf2f((u16)v[7]);
        }
    }
    f32x4 s0 = *(const f32x4*)&sdw[cg], s1 = *(const f32x4*)&sdw[cg + 4];
    f32x4 b0 = *(const f32x4*)&bdw[cg], b1 = *(const f32x4*)&bdw[cg + 4];
    short8 o;
    o[0] = (short)f2bf(fmaxf(acc[0] * s0[0] + b0[0], 0.f));
    o[1] = (short)f2bf(fmaxf(acc[1] * s0[1] + b0[1], 0.f));
    o[2] = (short)f2bf(fmaxf(acc[2] * s0[2] + b0[2], 0.f));
    o[3] = (short)f2bf(fmaxf(acc[3] * s0[3] + b0[3], 0.f));
    o[4] = (short)f2bf(fmaxf(acc[4] * s1[0] + b1[0], 0.f));
    o[5] = (short)f2bf(fmaxf(acc[5] * s1[1] + b1[1], 0.f));
    o[6] = (short)f2bf(fmaxf(acc[6] * s1[2] + b1[2], 0.f));
    o[7] = (short)f2bf(fmaxf(acc[7] * s1[3] + b1[3], 0.f));
    *(short8*)&dwout[p * 256 + cg] = o;
}

extern "C" void kernel_launch(void* const* d_in, const int* in_sizes, int n_in,
                              void* d_out, int out_size, void* d_ws, size_t ws_size,
                              hipStream_t stream) {
    const float* x = (const float*)d_in[0];
    const float* wq = (const float*)d_in[1];
    const float* sq = (const float*)d_in[2];
    const float* bq = (const float*)d_in[3];
    const float* wk = (const float*)d_in[4];
    const float* sk = (const float*)d_in[5];
    const float* bk = (const float*)d_in[6];
    const float* wv = (const float*)d_in[7];
    const float* sv = (const float*)d_in[8];
    const float* bv = (const float*)d_in[9];
    const float* posrq = (const float*)d_in[10];
    const float* posrk = (const float*)d_in[11];
    const float* poscq = (const float*)d_in[12];
    const float* posck = (const float*)d_in[13];
    const float* w_row = (const float*)d_in[14];
    const float* s_row = (const float*)d_in[15];
    const float* b_row = (const float*)d_in[16];
    const float* w_col = (const float*)d_in[17];
    const float* s_col = (const float*)d_in[18];
    const float* b_col = (const float*)d_in[19];
    const float* w_proj = (const float*)d_in[20];
    const float* s_proj = (const float*)d_in[21];
    const float* b_proj = (const float*)d_in[22];
    const float* w_sc = (const float*)d_in[23];
    const float* s_sc = (const float*)d_in[24];
    const float* b_sc = (const float*)d_in[25];
    const float* w_dw = (const float*)d_in[26];
    const float* s_dw = (const float*)d_in[27];
    const float* b_dw = (const float*)d_in[28];
    const float* w_pw = (const float*)d_in[29];
    const float* s_pw = (const float*)d_in[30];
    const float* b_pw = (const float*)d_in[31];
    float* out = (float*)d_out;

    float* fws = (float*)d_ws;
    float* qrow = fws;                   // [b][c=128][n] fp32
    float* krow = qrow + 131072;
    float* qcol = krow + 131072;
    float* kcol = qcol + 131072;
    float* vrow = kcol + 131072;         // [b][c=512][n]
    float* vcol = vrow + 524288;
    float* xr2  = vcol + 524288;         // [b][n][512] fp32
    float* xc2  = xr2 + 524288;
    float* wdwT = xc2 + 524288;          // [9][256]
    u16* xmb    = (u16*)(wdwT + 2304);            // [2048][256] bf16 means
    u16* xbf    = xmb + 524288;                   // [65536][256]
    u16* wqkvb  = xbf + (size_t)PTOT * 256;       // [768][256]
    u16* wscb   = wqkvb + 196608;                 // [256][256]
    u16* wprojb = wscb + 65536;                   // [256][512]
    u16* wpwb   = wprojb + 131072;                // [256][256]
    u16* wrb    = wpwb + 65536;                   // [512][512]
    u16* wcb    = wrb + 262144;                   // [512][512]
    u16* xxbf   = wcb + 262144;                   // [b][br][64][512]
    u16* scb    = xxbf + 1048576;                 // [65536][256]
    u16* dwb    = scb + (size_t)PTOT * 256;       // [65536][256]
    u16* abuf   = dwb + (size_t)PTOT * 256;       // [65536][512]
    u16* gate   = scb;                            // alias: sc dead after dw_kernel

    mean_kernel<<<dim3(Bn * Cc), 256, 0, stream>>>(x, xmb);
    xpose_kernel<<<dim3(64, 4, Bn), 256, 0, stream>>>(x, xbf);
    wconv_kernel<<<dim3(3840), 256, 0, stream>>>(
        wq, wk, wv, w_sc, w_proj, w_pw, w_row, w_col, w_dw,
        wqkvb, wscb, wprojb, wpwb, wrb, wcb, wdwT);
    gemm_qkv<<<dim3(6, 16), 256, 0, stream>>>(
        wqkvb, xmb, sq, bq, sk, bk, sv, bv,
        posrq, posrk, poscq, posck, qrow, krow, vrow, qcol, kcol, vcol);
    attn_kernel<<<dim3(128, 2), 64, 0, stream>>>(qrow, krow, vrow, qcol, kcol, vcol, xxbf);
    post_gemm<<<dim3(2, Bn, 2), 256, 0, stream>>>(
        xxbf, wrb, wcb, s_row, b_row, s_col, b_col, xr2, xc2);
    gemm_sc<<<dim3(2, 512), 256, 0, stream>>>(wscb, xbf, s_sc, b_sc, scb);
    dw_kernel<<<dim3(8192), 256, 0, stream>>>(scb, wdwT, s_dw, b_dw, dwb);
    gemm_v<<<dim3(4, 512), 256, 0, stream>>>(wqkvb + 65536, xbf, sv, bv, xr2, xc2, abuf);
    gemm_pw<<<dim3(2, 512), 256, 0, stream>>>(wpwb, dwb, s_pw, b_pw, gate);
    gemm_proj<<<dim3(2, 512), 256, 0, stream>>>(wprojb, abuf, s_proj, b_proj, gate, out);
}

// Round 6
// 490.386 us; speedup vs baseline: 8.1872x; 1.0685x over previous
//
#include <hip/hip_runtime.h>
#include <math.h>

typedef unsigned short u16;
typedef unsigned int u32;
typedef short short8 __attribute__((ext_vector_type(8)));
typedef float f32x4 __attribute__((ext_vector_type(4)));

#define Bn 16
#define Cc 256
#define Pp 4096
#define DHc 512
#define PTOT 65536   // Bn * Pp
#define SCALE 0.25f

__device__ __forceinline__ float bf2f(u16 u) {
    return __uint_as_float(((u32)u) << 16);
}
__device__ __forceinline__ u16 f2bf(float f) {
    u32 u = __float_as_uint(f);
    u32 lsb = (u >> 16) & 1u;
    u += 0x7fffu + lsb;  // round-to-nearest-even
    return (u16)(u >> 16);
}

// global -> LDS direct copy, 16 bytes per lane (LDS dest must be base + lane*16).
__device__ __forceinline__ void gload16(const u16* g, u16* l) {
    __builtin_amdgcn_global_load_lds(
        (const __attribute__((address_space(1))) void*)(uintptr_t)g,
        (__attribute__((address_space(3))) void*)(u32)(uintptr_t)l,
        16, 0, 0);
}

// ---------------- K1: means -> bf16 xmb [2048][256]; rows 0..1023 = (b,h) row-branch,
// rows 1024..2047 = (b,w) col-branch.
__global__ __launch_bounds__(256) void mean_kernel(
    const float* __restrict__ x, u16* __restrict__ xmb) {
    __shared__ float plane[64][65];
    int bc = blockIdx.x;
    int b = bc >> 8, c = bc & 255;
    const float* xp = x + (size_t)bc * Pp;
    int tid = threadIdx.x;
#pragma unroll
    for (int k = 0; k < 16; ++k) {
        int idx = tid + k * 256;
        plane[idx >> 6][idx & 63] = xp[idx];
    }
    __syncthreads();
    if (tid < 64) {
        float s = 0.f;
#pragma unroll
        for (int w = 0; w < 64; ++w) s += plane[tid][w];
        xmb[((size_t)b * 64 + tid) * 256 + c] = f2bf(s * (1.f / 64.f));
    } else if (tid < 128) {
        int w = tid - 64;
        float s = 0.f;
#pragma unroll
        for (int h = 0; h < 64; ++h) s += plane[h][w];
        xmb[((size_t)1024 + b * 64 + w) * 256 + c] = f2bf(s * (1.f / 64.f));
    }
}

// --------------------- K2: transpose x [b][c][p] -> xbf [b*P+p][c] bf16
__global__ __launch_bounds__(256) void xpose_kernel(
    const float* __restrict__ x, u16* __restrict__ xbf) {
    __shared__ float tile[64][65];
    int pb = blockIdx.x;
    int cb = blockIdx.y;
    int b = blockIdx.z;
    int t = threadIdx.x;
    int p_l = t & 63, c_q = t >> 6;
    const float* xp = x + ((size_t)b * Cc + cb * 64) * Pp + pb * 64;
#pragma unroll
    for (int rr = 0; rr < 16; ++rr) {
        int c_l = rr * 4 + c_q;
        tile[p_l][c_l] = xp[(size_t)c_l * Pp + p_l];
    }
    __syncthreads();
    int c_l2 = t & 63, p_q = t >> 6;
    u16* dst = xbf + ((size_t)b * Pp + pb * 64) * Cc + cb * 64;
#pragma unroll
    for (int rr = 0; rr < 16; ++rr) {
        int p_l2 = rr * 4 + p_q;
        dst[(size_t)p_l2 * Cc + c_l2] = f2bf(tile[p_l2][c_l2]);
    }
}

// -------------- K3: weights fp32 -> bf16; wq/wk/wv stacked into wqkvb [768][256]
__global__ __launch_bounds__(256) void wconv_kernel(
    const float* __restrict__ wq, const float* __restrict__ wk, const float* __restrict__ wv,
    const float* __restrict__ wsc, const float* __restrict__ wproj, const float* __restrict__ wpw,
    const float* __restrict__ wrow, const float* __restrict__ wcol,
    const float* __restrict__ wdw,
    u16* __restrict__ wqkvb, u16* __restrict__ wscb,
    u16* __restrict__ wprojb, u16* __restrict__ wpwb,
    u16* __restrict__ wrb, u16* __restrict__ wcb, float* __restrict__ wdwT) {
    int t = blockIdx.x * 256 + threadIdx.x;  // 983040 total
    if (t < 2304) wdwT[(t % 9) * 256 + (t / 9)] = wdw[t];
    if (t < 32768) wqkvb[t] = f2bf(wq[t]);
    else if (t < 65536) wqkvb[t] = f2bf(wk[t - 32768]);
    else if (t < 196608) wqkvb[t] = f2bf(wv[t - 65536]);
    else if (t < 262144) wscb[t - 196608] = f2bf(wsc[t - 196608]);
    else if (t < 393216) wprojb[t - 262144] = f2bf(wproj[t - 262144]);
    else if (t < 458752) wpwb[t - 393216] = f2bf(wpw[t - 393216]);
    else if (t < 720896) wrb[t - 458752] = f2bf(wrow[t - 458752]);
    else wcb[t - 720896] = f2bf(wcol[t - 720896]);
}

// ------------------------------------------------------------- MFMA GEMM mainloop
// D[o][p] = sum_k W[o][k] * X[p][k], 128x128 tile, BK=32, 4 waves (2x2 of 64x64).
__device__ __forceinline__ void gemm_mainloop(
    const u16* __restrict__ W, const u16* __restrict__ X, int K,
    int o0, size_t prow0, u16* ldsA, u16* ldsB, f32x4 (&acc)[4][4]) {
    int t = threadIdx.x;
    int w = t >> 6, lane = t & 63;
    int sr = (w << 5) + (lane >> 2);
    int ks = (lane & 3) * 8;
    const u16* gA = W + (size_t)(o0 + sr) * K + ks;
    const u16* gB = X + (prow0 + sr) * K + ks;
    u16* lA = ldsA + sr * 32 + ks;
    u16* lB = ldsB + sr * 32 + ks;
    int wo = (w >> 1) * 64, wp = (w & 1) * 64;
    const u16* fA = ldsA + (wo + (lane & 15)) * 32 + ((lane >> 4) * 8);
    const u16* fB = ldsB + (wp + (lane & 15)) * 32 + ((lane >> 4) * 8);

    for (int k0 = 0; k0 < K; k0 += 32) {
        if (k0) __syncthreads();
        gload16(gA + k0, lA);
        gload16(gA + k0 + (size_t)16 * K, lA + 16 * 32);
        gload16(gB + k0, lB);
        gload16(gB + k0 + (size_t)16 * K, lB + 16 * 32);
        __syncthreads();
        short8 a[4], b[4];
#pragma unroll
        for (int i = 0; i < 4; ++i) a[i] = *(const short8*)(fA + i * 16 * 32);
#pragma unroll
        for (int j = 0; j < 4; ++j) b[j] = *(const short8*)(fB + j * 16 * 32);
#pragma unroll
        for (int i = 0; i < 4; ++i)
#pragma unroll
            for (int j = 0; j < 4; ++j)
                acc[i][j] = __builtin_amdgcn_mfma_f32_16x16x32_bf16(a[i], b[j], acc[i][j], 0, 0, 0);
    }
}

// ---------- K4: q/k/v embeddings as one GEMM: [768]x[2048 rows]xK=256.
__global__ __launch_bounds__(256) void gemm_qkv(
    const u16* __restrict__ Wb, const u16* __restrict__ X,
    const float* __restrict__ sq, const float* __restrict__ bq,
    const float* __restrict__ sk, const float* __restrict__ bk,
    const float* __restrict__ sv, const float* __restrict__ bv,
    const float* __restrict__ posrq, const float* __restrict__ posrk,
    const float* __restrict__ poscq, const float* __restrict__ posck,
    float* __restrict__ qrow, float* __restrict__ krow, float* __restrict__ vrow,
    float* __restrict__ qcol, float* __restrict__ kcol, float* __restrict__ vcol) {
    __shared__ u16 ldsA[128 * 32];
    __shared__ u16 ldsB[128 * 32];
    f32x4 acc[4][4];
#pragma unroll
    for (int i = 0; i < 4; ++i)
#pragma unroll
        for (int j = 0; j < 4; ++j) acc[i][j] = (f32x4){0.f, 0.f, 0.f, 0.f};
    int o0 = blockIdx.x * 128;          // 0..5
    size_t prow0 = (size_t)blockIdx.y * 128;  // 0..15
    gemm_mainloop(Wb, X, 256, o0, prow0, ldsA, ldsB, acc);

    int lane = threadIdx.x & 63, w = threadIdx.x >> 6;
    int wo = (w >> 1) * 64, wp = (w & 1) * 64;
    int quad = lane >> 4, cn = lane & 15;
#pragma unroll
    for (int j = 0; j < 4; ++j) {
        int p = (int)prow0 + wp + j * 16 + cn;
        int branch = p >> 10, loc = p & 1023;
        int b = loc >> 6, n = loc & 63;
        float coords = 0.25f * (float)n - 0.375f;
        coords = fminf(fmaxf(coords, 0.f), 15.f);
        int lo = (int)floorf(coords);
        int hi = min(lo + 1, 15);
        float tt = coords - (float)lo;
#pragma unroll
        for (int i = 0; i < 4; ++i) {
            int o = o0 + wo + i * 16 + quad * 4;
            if (o < 128) {
                const float* pos = branch ? poscq : posrq;
                float* dst = branch ? qcol : qrow;
#pragma unroll
                for (int r = 0; r < 4; ++r) {
                    int c = o + r;
                    float pv = pos[c * 16 + lo] * (1.f - tt) + pos[c * 16 + hi] * tt;
                    dst[b * 8192 + c * 64 + n] = acc[i][j][r] * sq[c] + bq[c] + pv;
                }
            } else if (o < 256) {
                const float* pos = branch ? posck : posrk;
                float* dst = branch ? kcol : krow;
#pragma unroll
                for (int r = 0; r < 4; ++r) {
                    int c = o - 128 + r;
                    float pv = pos[c * 16 + lo] * (1.f - tt) + pos[c * 16 + hi] * tt;
                    dst[b * 8192 + c * 64 + n] = acc[i][j][r] * sk[c] + bk[c] + pv;
                }
            } else {
                float* dst = branch ? vcol : vrow;
#pragma unroll
                for (int r = 0; r < 4; ++r) {
                    int c = o - 256 + r;
                    dst[b * 32768 + c * 64 + n] = acc[i][j][r] * sv[c] + bv[c];
                }
            }
        }
    }
}

// ---------------- K5: axial attention, 512 threads = 8 waves per (b,head,branch).
// thread = (n = t&63, d-octet = t>>6). Scores recomputed per wave (cheap);
// PV split 8x across waves. Emits relu(xx) bf16 transposed [b][br][n][i=h*64+d].
__global__ __launch_bounds__(512) void attn_kernel(
    const float* __restrict__ qr, const float* __restrict__ kr, const float* __restrict__ vr,
    const float* __restrict__ qc, const float* __restrict__ kc, const float* __restrict__ vc,
    u16* __restrict__ xxbf) {
    int branch = blockIdx.y;
    const float* q = branch ? qc : qr;
    const float* k = branch ? kc : kr;
    const float* v = branch ? vc : vr;
    int bh = blockIdx.x;
    int b = bh >> 3, h = bh & 7;
    __shared__ float qs[16][64], ks[16][64], vs[64][64];
    int t = threadIdx.x;
#pragma unroll
    for (int i = t; i < 1024; i += 512) {
        int c = i >> 6, nn = i & 63;
        qs[c][nn] = q[b * 8192 + (h * 16 + c) * 64 + nn];
        ks[c][nn] = k[b * 8192 + (h * 16 + c) * 64 + nn];
    }
#pragma unroll
    for (int i = t; i < 4096; i += 512) {
        int d = i >> 6, nn = i & 63;
        vs[d][nn] = v[b * 32768 + (h * 64 + d) * 64 + nn];
    }
    __syncthreads();

    int n = t & 63, dq = t >> 6;  // dq in [0,8)
    float qv[16];
#pragma unroll
    for (int c = 0; c < 16; ++c) qv[c] = qs[c][n];

    float s[64];
    float mx = -1e30f;
    for (int m = 0; m < 64; ++m) {
        float acc = 0.f;
#pragma unroll
        for (int c = 0; c < 16; ++c) acc += qv[c] * ks[c][m];
        acc *= SCALE;
        s[m] = acc;
        mx = fmaxf(mx, acc);
    }
    float sum = 0.f;
    for (int m = 0; m < 64; ++m) {
        s[m] = __expf(s[m] - mx);
        sum += s[m];
    }
    float inv = 1.f / sum;
    u16* dst = xxbf + (((size_t)(b * 2 + branch)) * 64 + n) * 512 + h * 64 + dq * 8;
#pragma unroll
    for (int dd = 0; dd < 8; ++dd) {
        int d = dq * 8 + dd;
        float acc = 0.f;
#pragma unroll 8
        for (int m = 0; m < 64; ++m) acc += s[m] * vs[d][m];
        dst[dd] = f2bf(fmaxf(acc * inv, 0.f));
    }
}

// -------- K6: post cbn via MFMA. per (o-half, b, branch): M=64(n) N=256(o) K=512.
__global__ __launch_bounds__(256) void post_gemm(
    const u16* __restrict__ xxbf, const u16* __restrict__ wrb, const u16* __restrict__ wcb,
    const float* __restrict__ s_row, const float* __restrict__ b_row,
    const float* __restrict__ s_col, const float* __restrict__ b_col,
    float* __restrict__ xr2, float* __restrict__ xc2) {
    __shared__ u16 ldsA[64 * 32];
    __shared__ u16 ldsB[256 * 32];
    int o0 = blockIdx.x * 256;
    int b = blockIdx.y;
    int branch = blockIdx.z;
    const u16* A = xxbf + ((size_t)(b * 2 + branch)) * 64 * 512;
    const u16* W = branch ? wcb : wrb;
    const float* ss = branch ? s_col : s_row;
    const float* bb = branch ? b_col : b_row;
    float* dst = (branch ? xc2 : xr2) + (size_t)b * 32768;

    f32x4 acc[4][4];
#pragma unroll
    for (int i = 0; i < 4; ++i)
#pragma unroll
        for (int j = 0; j < 4; ++j) acc[i][j] = (f32x4){0.f, 0.f, 0.f, 0.f};

    int t = threadIdx.x, w = t >> 6, lane = t & 63;
    int ks = (t & 3) * 8;
    const u16* gA = A + (size_t)(t >> 2) * 512 + ks;
    const u16* gB = W + (size_t)(o0 + (t >> 2)) * 512 + ks;
    u16* lA = ldsA + (t >> 2) * 32 + ks;
    u16* lB = ldsB + (t >> 2) * 32 + ks;
    const u16* fA = ldsA + (lane & 15) * 32 + ((lane >> 4) * 8);
    const u16* fB = ldsB + (w * 64 + (lane & 15)) * 32 + ((lane >> 4) * 8);

    for (int k0 = 0; k0 < 512; k0 += 32) {
        if (k0) __syncthreads();
        gload16(gA + k0, lA);
#pragma unroll
        for (int r = 0; r < 4; ++r)
            gload16(gB + k0 + (size_t)r * 64 * 512, lB + r * 64 * 32);
        __syncthreads();
        short8 a[4], bfr[4];
#pragma unroll
        for (int i = 0; i < 4; ++i) a[i] = *(const short8*)(fA + i * 16 * 32);
#pragma unroll
        for (int j = 0; j < 4; ++j) bfr[j] = *(const short8*)(fB + j * 16 * 32);
#pragma unroll
        for (int i = 0; i < 4; ++i)
#pragma unroll
            for (int j = 0; j < 4; ++j)
                acc[i][j] = __builtin_amdgcn_mfma_f32_16x16x32_bf16(a[i], bfr[j], acc[i][j], 0, 0, 0);
    }

    int quad = lane >> 4, cn = lane & 15;
#pragma unroll
    for (int i = 0; i < 4; ++i)
#pragma unroll
        for (int j = 0; j < 4; ++j) {
            int o = o0 + w * 64 + j * 16 + cn;
            float sv_ = ss[o], bv_ = bb[o];
#pragma unroll
            for (int r = 0; r < 4; ++r) {
                int n = i * 16 + quad * 4 + r;
                dst[n * 512 + o] = acc[i][j][r] * sv_ + bv_;
            }
        }
}

// ------------------------------------- G1: sc = cbn(x, w_sc)  -> scb bf16 [p][256]
__global__ __launch_bounds__(256) void gemm_sc(
    const u16* __restrict__ Wb, const u16* __restrict__ X,
    const float* __restrict__ s, const float* __restrict__ bb, u16* __restrict__ outb) {
    __shared__ u16 ldsA[128 * 32];
    __shared__ u16 ldsB[128 * 32];
    f32x4 acc[4][4];
#pragma unroll
    for (int i = 0; i < 4; ++i)
#pragma unroll
        for (int j = 0; j < 4; ++j) acc[i][j] = (f32x4){0.f, 0.f, 0.f, 0.f};
    int o0 = blockIdx.x * 128;
    size_t prow0 = (size_t)blockIdx.y * 128;
    gemm_mainloop(Wb, X, 256, o0, prow0, ldsA, ldsB, acc);

    int lane = threadIdx.x & 63, w = threadIdx.x >> 6;
    int wo = (w >> 1) * 64, wp = (w & 1) * 64;
    int quad = lane >> 4, cn = lane & 15;
#pragma unroll
    for (int i = 0; i < 4; ++i) {
        int ob = o0 + wo + i * 16 + quad * 4;
        f32x4 s4 = *(const f32x4*)&s[ob];
        f32x4 b4 = *(const f32x4*)&bb[ob];
#pragma unroll
        for (int j = 0; j < 4; ++j) {
            size_t p = prow0 + wp + j * 16 + cn;
            ushort4 o4;
            o4.x = f2bf(acc[i][j][0] * s4[0] + b4[0]);
            o4.y = f2bf(acc[i][j][1] * s4[1] + b4[1]);
            o4.z = f2bf(acc[i][j][2] * s4[2] + b4[2]);
            o4.w = f2bf(acc[i][j][3] * s4[3] + b4[3]);
            *(ushort4*)&outb[p * 256 + ob] = o4;
        }
    }
}

// ------------- G2: abuf = relu(cbn(x,wv) + xr2 + xc2) -> bf16 [p][512]
__global__ __launch_bounds__(256) void gemm_v(
    const u16* __restrict__ Wb, const u16* __restrict__ X,
    const float* __restrict__ s, const float* __restrict__ bb,
    const float* __restrict__ xr2, const float* __restrict__ xc2, u16* __restrict__ outb) {
    __shared__ u16 ldsA[128 * 32];
    __shared__ u16 ldsB[128 * 32];
    f32x4 acc[4][4];
#pragma unroll
    for (int i = 0; i < 4; ++i)
#pragma unroll
        for (int j = 0; j < 4; ++j) acc[i][j] = (f32x4){0.f, 0.f, 0.f, 0.f};
    int o0 = blockIdx.x * 128;
    size_t prow0 = (size_t)blockIdx.y * 128;
    gemm_mainloop(Wb, X, 256, o0, prow0, ldsA, ldsB, acc);

    int lane = threadIdx.x & 63, w = threadIdx.x >> 6;
    int wo = (w >> 1) * 64, wp = (w & 1) * 64;
    int quad = lane >> 4, cn = lane & 15;
#pragma unroll
    for (int i = 0; i < 4; ++i) {
        int ob = o0 + wo + i * 16 + quad * 4;
        f32x4 s4 = *(const f32x4*)&s[ob];
        f32x4 b4 = *(const f32x4*)&bb[ob];
#pragma unroll
        for (int j = 0; j < 4; ++j) {
            size_t p = prow0 + wp + j * 16 + cn;
            int bi = (int)(p >> 12), hh = (int)((p >> 6) & 63), ww = (int)(p & 63);
            f32x4 ra = *(const f32x4*)&xr2[(size_t)bi * 32768 + hh * 512 + ob];
            f32x4 ca = *(const f32x4*)&xc2[(size_t)bi * 32768 + ww * 512 + ob];
            ushort4 o4;
            o4.x = f2bf(fmaxf(acc[i][j][0] * s4[0] + b4[0] + ra[0] + ca[0], 0.f));
            o4.y = f2bf(fmaxf(acc[i][j][1] * s4[1] + b4[1] + ra[1] + ca[1], 0.f));
            o4.z = f2bf(fmaxf(acc[i][j][2] * s4[2] + b4[2] + ra[2] + ca[2], 0.f));
            o4.w = f2bf(fmaxf(acc[i][j][3] * s4[3] + b4[3] + ra[3] + ca[3], 0.f));
            *(ushort4*)&outb[p * 512 + ob] = o4;
        }
    }
}

// ------------- G3: gate = h_sigmoid(cbn(dwout, w_pw)) -> bf16 [p][256]
__global__ __launch_bounds__(256) void gemm_pw(
    const u16* __restrict__ Wb, const u16* __restrict__ X,
    const float* __restrict__ s, const float* __restrict__ bb, u16* __restrict__ outb) {
    __shared__ u16 ldsA[128 * 32];
    __shared__ u16 ldsB[128 * 32];
    f32x4 acc[4][4];
#pragma unroll
    for (int i = 0; i < 4; ++i)
#pragma unroll
        for (int j = 0; j < 4; ++j) acc[i][j] = (f32x4){0.f, 0.f, 0.f, 0.f};
    int o0 = blockIdx.x * 128;
    size_t prow0 = (size_t)blockIdx.y * 128;
    gemm_mainloop(Wb, X, 256, o0, prow0, ldsA, ldsB, acc);

    int lane = threadIdx.x & 63, w = threadIdx.x >> 6;
    int wo = (w >> 1) * 64, wp = (w & 1) * 64;
    int quad = lane >> 4, cn = lane & 15;
#pragma unroll
    for (int i = 0; i < 4; ++i) {
        int ob = o0 + wo + i * 16 + quad * 4;
        f32x4 s4 = *(const f32x4*)&s[ob];
        f32x4 b4 = *(const f32x4*)&bb[ob];
#pragma unroll
        for (int j = 0; j < 4; ++j) {
            size_t p = prow0 + wp + j * 16 + cn;
            ushort4 o4;
            o4.x = f2bf(fminf(fmaxf(acc[i][j][0] * s4[0] + b4[0] + 3.f, 0.f), 6.f) * (1.f / 6.f));
            o4.y = f2bf(fminf(fmaxf(acc[i][j][1] * s4[1] + b4[1] + 3.f, 0.f), 6.f) * (1.f / 6.f));
            o4.z = f2bf(fminf(fmaxf(acc[i][j][2] * s4[2] + b4[2] + 3.f, 0.f), 6.f) * (1.f / 6.f));
            o4.w = f2bf(fminf(fmaxf(acc[i][j][3] * s4[3] + b4[3] + 3.f, 0.f), 6.f) * (1.f / 6.f));
            *(ushort4*)&outb[p * 256 + ob] = o4;
        }
    }
}

// ------------- G4: out[b][o][p] = gate[p][o] * cbn(abuf, w_proj)   (K=512, fp32 out)
__global__ __launch_bounds__(256) void gemm_proj(
    const u16* __restrict__ Wb, const u16* __restrict__ X,
    const float* __restrict__ s, const float* __restrict__ bb,
    const u16* __restrict__ gate, float* __restrict__ out) {
    __shared__ u16 ldsA[128 * 32];
    __shared__ u16 ldsB[128 * 32];
    f32x4 acc[4][4];
#pragma unroll
    for (int i = 0; i < 4; ++i)
#pragma unroll
        for (int j = 0; j < 4; ++j) acc[i][j] = (f32x4){0.f, 0.f, 0.f, 0.f};
    int o0 = blockIdx.x * 128;
    size_t prow0 = (size_t)blockIdx.y * 128;
    gemm_mainloop(Wb, X, 512, o0, prow0, ldsA, ldsB, acc);

    int lane = threadIdx.x & 63, w = threadIdx.x >> 6;
    int wo = (w >> 1) * 64, wp = (w & 1) * 64;
    int quad = lane >> 4, cn = lane & 15;
#pragma unroll
    for (int i = 0; i < 4; ++i) {
        int ob = o0 + wo + i * 16 + quad * 4;
        f32x4 s4 = *(const f32x4*)&s[ob];
        f32x4 b4 = *(const f32x4*)&bb[ob];
#pragma unroll
        for (int j = 0; j < 4; ++j) {
            size_t p = prow0 + wp + j * 16 + cn;
            int bi = (int)(p >> 12), pl = (int)(p & 4095);
            ushort4 gv = *(const ushort4*)&gate[p * 256 + ob];
            float* op = out + (size_t)bi * 1048576 + (size_t)ob * 4096 + pl;
            op[0 * 4096] = bf2f(gv.x) * (acc[i][j][0] * s4[0] + b4[0]);
            op[1 * 4096] = bf2f(gv.y) * (acc[i][j][1] * s4[1] + b4[1]);
            op[2 * 4096] = bf2f(gv.z) * (acc[i][j][2] * s4[2] + b4[2]);
            op[3 * 4096] = bf2f(gv.w) * (acc[i][j][3] * s4[3] + b4[3]);
        }
    }
}

// --------------- K7: depthwise 3x3 + affine + relu, [p][c], 8 channels/thread
__global__ __launch_bounds__(256) void dw_kernel(
    const u16* __restrict__ sc, const float* __restrict__ wdwT,
    const float* __restrict__ sdw, const float* __restrict__ bdw, u16* __restrict__ dwout) {
    int t = blockIdx.x * 256 + threadIdx.x;  // PTOT * 32
    int cg = (t & 31) * 8;
    size_t p = (size_t)(t >> 5);
    int h = (int)((p >> 6) & 63), w_ = (int)(p & 63);
    float acc[8] = {0.f, 0.f, 0.f, 0.f, 0.f, 0.f, 0.f, 0.f};
#pragma unroll
    for (int ky = 0; ky < 3; ++ky) {
        int hh = h + ky - 1;
        if (hh < 0 || hh > 63) continue;
#pragma unroll
        for (int kx = 0; kx < 3; ++kx) {
            int wx = w_ + kx - 1;
            if (wx < 0 || wx > 63) continue;
            size_t pp = (size_t)((long long)p + (ky - 1) * 64 + (kx - 1));
            short8 v = *(const short8*)&sc[pp * 256 + cg];
            const float* wt = &wdwT[(ky * 3 + kx) * 256 + cg];
            f32x4 w0 = *(const f32x4*)wt;
            f32x4 w1 = *(const f32x4*)(wt + 4);
            acc[0] += w0[0] * bf2f((u16)v[0]); acc[1] += w0[1] * bf2f((u16)v[1]);
            acc[2] += w0[2] * bf2f((u16)v[2]); acc[3] += w0[3] * bf2f((u16)v[3]);
            acc[4] += w1[0] * bf2f((u16)v[4]); acc[5] += w1[1] * bf2f((u16)v[5]);
            acc[6] += w1[2] * bf2f((u16)v[6]); acc[7] += w1[3] * bf2f((u16)v[7]);
        }
    }
    f32x4 s0 = *(const f32x4*)&sdw[cg], s1 = *(const f32x4*)&sdw[cg + 4];
    f32x4 b0 = *(const f32x4*)&bdw[cg], b1 = *(const f32x4*)&bdw[cg + 4];
    short8 o;
    o[0] = (short)f2bf(fmaxf(acc[0] * s0[0] + b0[0], 0.f));
    o[1] = (short)f2bf(fmaxf(acc[1] * s0[1] + b0[1], 0.f));
    o[2] = (short)f2bf(fmaxf(acc[2] * s0[2] + b0[2], 0.f));
    o[3] = (short)f2bf(fmaxf(acc[3] * s0[3] + b0[3], 0.f));
    o[4] = (short)f2bf(fmaxf(acc[4] * s1[0] + b1[0], 0.f));
    o[5] = (short)f2bf(fmaxf(acc[5] * s1[1] + b1[1], 0.f));
    o[6] = (short)f2bf(fmaxf(acc[6] * s1[2] + b1[2], 0.f));
    o[7] = (short)f2bf(fmaxf(acc[7] * s1[3] + b1[3], 0.f));
    *(short8*)&dwout[p * 256 + cg] = o;
}

extern "C" void kernel_launch(void* const* d_in, const int* in_sizes, int n_in,
                              void* d_out, int out_size, void* d_ws, size_t ws_size,
                              hipStream_t stream) {
    const float* x = (const float*)d_in[0];
    const float* wq = (const float*)d_in[1];
    const float* sq = (const float*)d_in[2];
    const float* bq = (const float*)d_in[3];
    const float* wk = (const float*)d_in[4];
    const float* sk = (const float*)d_in[5];
    const float* bk = (const float*)d_in[6];
    const float* wv = (const float*)d_in[7];
    const float* sv = (const float*)d_in[8];
    const float* bv = (const float*)d_in[9];
    const float* posrq = (const float*)d_in[10];
    const float* posrk = (const float*)d_in[11];
    const float* poscq = (const float*)d_in[12];
    const float* posck = (const float*)d_in[13];
    const float* w_row = (const float*)d_in[14];
    const float* s_row = (const float*)d_in[15];
    const float* b_row = (const float*)d_in[16];
    const float* w_col = (const float*)d_in[17];
    const float* s_col = (const float*)d_in[18];
    const float* b_col = (const float*)d_in[19];
    const float* w_proj = (const float*)d_in[20];
    const float* s_proj = (const float*)d_in[21];
    const float* b_proj = (const float*)d_in[22];
    const float* w_sc = (const float*)d_in[23];
    const float* s_sc = (const float*)d_in[24];
    const float* b_sc = (const float*)d_in[25];
    const float* w_dw = (const float*)d_in[26];
    const float* s_dw = (const float*)d_in[27];
    const float* b_dw = (const float*)d_in[28];
    const float* w_pw = (const float*)d_in[29];
    const float* s_pw = (const float*)d_in[30];
    const float* b_pw = (const float*)d_in[31];
    float* out = (float*)d_out;

    float* fws = (float*)d_ws;
    float* qrow = fws;                   // [b][c=128][n] fp32
    float* krow = qrow + 131072;
    float* qcol = krow + 131072;
    float* kcol = qcol + 131072;
    float* vrow = kcol + 131072;         // [b][c=512][n]
    float* vcol = vrow + 524288;
    float* xr2  = vcol + 524288;         // [b][n][512] fp32
    float* xc2  = xr2 + 524288;
    float* wdwT = xc2 + 524288;          // [9][256]
    u16* xmb    = (u16*)(wdwT + 2304);            // [2048][256] bf16 means
    u16* xbf    = xmb + 524288;                   // [65536][256]
    u16* wqkvb  = xbf + (size_t)PTOT * 256;       // [768][256]
    u16* wscb   = wqkvb + 196608;                 // [256][256]
    u16* wprojb = wscb + 65536;                   // [256][512]
    u16* wpwb   = wprojb + 131072;                // [256][256]
    u16* wrb    = wpwb + 65536;                   // [512][512]
    u16* wcb    = wrb + 262144;                   // [512][512]
    u16* xxbf   = wcb + 262144;                   // [b][br][64][512]
    u16* scb    = xxbf + 1048576;                 // [65536][256]
    u16* dwb    = scb + (size_t)PTOT * 256;       // [65536][256]
    u16* abuf   = dwb + (size_t)PTOT * 256;       // [65536][512]
    u16* gate   = scb;                            // alias: sc dead after dw_kernel

    mean_kernel<<<dim3(Bn * Cc), 256, 0, stream>>>(x, xmb);
    xpose_kernel<<<dim3(64, 4, Bn), 256, 0, stream>>>(x, xbf);
    wconv_kernel<<<dim3(3840), 256, 0, stream>>>(
        wq, wk, wv, w_sc, w_proj, w_pw, w_row, w_col, w_dw,
        wqkvb, wscb, wprojb, wpwb, wrb, wcb, wdwT);
    gemm_qkv<<<dim3(6, 16), 256, 0, stream>>>(
        wqkvb, xmb, sq, bq, sk, bk, sv, bv,
        posrq, posrk, poscq, posck, qrow, krow, vrow, qcol, kcol, vcol);
    attn_kernel<<<dim3(128, 2), 512, 0, stream>>>(qrow, krow, vrow, qcol, kcol, vcol, xxbf);
    post_gemm<<<dim3(2, Bn, 2), 256, 0, stream>>>(
        xxbf, wrb, wcb, s_row, b_row, s_col, b_col, xr2, xc2);
    gemm_sc<<<dim3(2, 512), 256, 0, stream>>>(wscb, xbf, s_sc, b_sc, scb);
    dw_kernel<<<dim3(8192), 256, 0, stream>>>(scb, wdwT, s_dw, b_dw, dwb);
    gemm_v<<<dim3(4, 512), 256, 0, stream>>>(wqkvb + 65536, xbf, sv, bv, xr2, xc2, abuf);
    gemm_pw<<<dim3(2, 512), 256, 0, stream>>>(wpwb, dwb, s_pw, b_pw, gate);
    gemm_proj<<<dim3(2, 512), 256, 0, stream>>>(wprojb, abuf, s_proj, b_proj, gate, out);
}